// Round 6
// baseline (502.561 us; speedup 1.0000x reference)
//
#include <hip/hip_runtime.h>
#include <hip/hip_bf16.h>

// ProjectedCGCraig on MI355X (gfx950).
//   x = A^T G^{-1} b,  G = A A^T (512x512)
//   d = projected CG with P v = v - A^T G^{-1} A v
// LESSON (R3): per-iteration projection must be refinement-exact (<=1e-9).
// LESSON (R5): CG scalars MEASURED fresh from stored fp32 vectors each iter.
// LESSON (R7): grid.sync() ~28us; launches (~2.2us) are the cheap grid sync.
// LESSON (R9->R10): LAST-BLOCK-ticket fold REGRESSED ~+100us. Launch
//   boundary IS the cheap handoff.
// R11: CG fused update (k_mv_B4u replicated-reduce, ping-pong p/r).
// R12/R13: Chebyshev init on FIXED MP interval [0.35,2.0]; CG=5; cubic refine.
// R14 (this round):
//   (a) aat REWRITE: old 4x4 micro-tile = 16 FMA / 2 ds_read_b128 -> LDS-read
//       bound: 4096 b128 x 12cyc = 20.5us/block x 2 blocks/CU = 41us (exact
//       match). New 8x8 micro-tile (128^2 tile, z=16, 256 blocks): ratio 64/4
//       -> ~23us LDS-serial. Operands split as [col, col+64] float4 pairs (all
//       LDS reads <=2-way = free), row stride padded to 130 (staging writes
//       2-way, was 8-way). 66.5KB static LDS (gfx950 allows 160KB; m201 used
//       128KB). P partials now 16 slices.
//   (b) DEGREE-2 Chebyshev init: X0 = c0 I + c1 G + c2 G^2 on [0.35,2.0].
//       E0 = 1/T3(1.4242) = 0.1373; 2 NS iters -> E = 3.55e-4; cubic ->
//       4.5e-11 << 1e-9 (22x margin, tolerates lam_max to 2.28 = 15 sigma).
//       G^2 partials via EXISTING k_ns_a(G,G,P) + 2us combine. NS 3->2.
// M=512, N=4096 fixed.

#define Mrows 512
#define Ncols 4096
#define CG_ITERS 5
#define AAT_PAD 130

__device__ __forceinline__ float wredF(float v) {
#pragma unroll
  for (int off = 32; off; off >>= 1) v += __shfl_down(v, off, 64);
  return v;
}
__device__ __forceinline__ double wredD(double v) {
#pragma unroll
  for (int off = 32; off; off >>= 1) v += __shfl_down(v, off, 64);
  return v;
}

// ---------------------------------------------------------------------------
// Partial AAT: slice bz = A[bi..+128][Kb..+256] * A[bj..+128][..]^T.
// grid (4,4,16), 256 thr, 8x8 micro-tile as 2x2 float4 groups at col/col+64.
// R14(a): LDS-read-ratio 64FMA/4reads; dbuf, 1 barrier/step, reg prefetch.
// ---------------------------------------------------------------------------
__global__ __launch_bounds__(256) void k_aat_part(const float* __restrict__ A,
                                                  float* __restrict__ P) {
  __shared__ float At[2][32][AAT_PAD];
  __shared__ float Bt[2][32][AAT_PAD];
  const int tid = threadIdx.x;
  const int tx = tid & 15, ty = tid >> 4;
  const int bj = blockIdx.x * 128, bi = blockIdx.y * 128;
  const int Kb = blockIdx.z * 256;
  const int ar = tid >> 3, ak = tid & 7;   // staging: row ar+32l, K-offset ak*4
  const int ak4 = ak * 4, ty4 = ty * 4, tx4 = tx * 4;
  const float* pa0 = &A[(size_t)(bi + ar) * Ncols + Kb + ak4];
  const float* pa1 = pa0 + (size_t)32 * Ncols;
  const float* pa2 = pa0 + (size_t)64 * Ncols;
  const float* pa3 = pa0 + (size_t)96 * Ncols;
  const float* pb0 = &A[(size_t)(bj + ar) * Ncols + Kb + ak4];
  const float* pb1 = pb0 + (size_t)32 * Ncols;
  const float* pb2 = pb0 + (size_t)64 * Ncols;
  const float* pb3 = pb0 + (size_t)96 * Ncols;
  float4 ra0 = *(const float4*)pa0, ra1 = *(const float4*)pa1;
  float4 ra2 = *(const float4*)pa2, ra3 = *(const float4*)pa3;
  float4 rb0 = *(const float4*)pb0, rb1 = *(const float4*)pb1;
  float4 rb2 = *(const float4*)pb2, rb3 = *(const float4*)pb3;
  float4 c[8][2];
#pragma unroll
  for (int i = 0; i < 8; i++) {
    c[i][0] = make_float4(0.f, 0.f, 0.f, 0.f);
    c[i][1] = make_float4(0.f, 0.f, 0.f, 0.f);
  }
  for (int s = 0; s < 8; ++s) {
    float (*Atc)[AAT_PAD] = At[s & 1];
    float (*Btc)[AAT_PAD] = Bt[s & 1];
    Atc[ak4 + 0][ar] = ra0.x; Atc[ak4 + 1][ar] = ra0.y;
    Atc[ak4 + 2][ar] = ra0.z; Atc[ak4 + 3][ar] = ra0.w;
    Atc[ak4 + 0][ar + 32] = ra1.x; Atc[ak4 + 1][ar + 32] = ra1.y;
    Atc[ak4 + 2][ar + 32] = ra1.z; Atc[ak4 + 3][ar + 32] = ra1.w;
    Atc[ak4 + 0][ar + 64] = ra2.x; Atc[ak4 + 1][ar + 64] = ra2.y;
    Atc[ak4 + 2][ar + 64] = ra2.z; Atc[ak4 + 3][ar + 64] = ra2.w;
    Atc[ak4 + 0][ar + 96] = ra3.x; Atc[ak4 + 1][ar + 96] = ra3.y;
    Atc[ak4 + 2][ar + 96] = ra3.z; Atc[ak4 + 3][ar + 96] = ra3.w;
    Btc[ak4 + 0][ar] = rb0.x; Btc[ak4 + 1][ar] = rb0.y;
    Btc[ak4 + 2][ar] = rb0.z; Btc[ak4 + 3][ar] = rb0.w;
    Btc[ak4 + 0][ar + 32] = rb1.x; Btc[ak4 + 1][ar + 32] = rb1.y;
    Btc[ak4 + 2][ar + 32] = rb1.z; Btc[ak4 + 3][ar + 32] = rb1.w;
    Btc[ak4 + 0][ar + 64] = rb2.x; Btc[ak4 + 1][ar + 64] = rb2.y;
    Btc[ak4 + 2][ar + 64] = rb2.z; Btc[ak4 + 3][ar + 64] = rb2.w;
    Btc[ak4 + 0][ar + 96] = rb3.x; Btc[ak4 + 1][ar + 96] = rb3.y;
    Btc[ak4 + 2][ar + 96] = rb3.z; Btc[ak4 + 3][ar + 96] = rb3.w;
    __syncthreads();
    if (s < 7) {
      const int off = (s + 1) * 32;
      ra0 = *(const float4*)(pa0 + off); ra1 = *(const float4*)(pa1 + off);
      ra2 = *(const float4*)(pa2 + off); ra3 = *(const float4*)(pa3 + off);
      rb0 = *(const float4*)(pb0 + off); rb1 = *(const float4*)(pb1 + off);
      rb2 = *(const float4*)(pb2 + off); rb3 = *(const float4*)(pb3 + off);
    }
#pragma unroll
    for (int kk = 0; kk < 32; kk++) {
      const float4 a0 = *(const float4*)&Atc[kk][ty4];
      const float4 a1 = *(const float4*)&Atc[kk][64 + ty4];
      const float4 b0 = *(const float4*)&Btc[kk][tx4];
      const float4 b1 = *(const float4*)&Btc[kk][64 + tx4];
      const float av[8] = {a0.x, a0.y, a0.z, a0.w, a1.x, a1.y, a1.z, a1.w};
#pragma unroll
      for (int i = 0; i < 8; i++) {
        c[i][0].x += av[i] * b0.x; c[i][0].y += av[i] * b0.y;
        c[i][0].z += av[i] * b0.z; c[i][0].w += av[i] * b0.w;
        c[i][1].x += av[i] * b1.x; c[i][1].y += av[i] * b1.y;
        c[i][1].z += av[i] * b1.z; c[i][1].w += av[i] * b1.w;
      }
    }
  }
  float* Co = P + (size_t)blockIdx.z * 262144;
#pragma unroll
  for (int i = 0; i < 8; i++) {
    const int row = bi + ((i < 4) ? (ty4 + i) : (64 + ty4 + (i - 4)));
    const size_t o = (size_t)row * Mrows + bj;
    *(float4*)&Co[o + tx4]      = c[i][0];
    *(float4*)&Co[o + 64 + tx4] = c[i][1];
  }
}

// ---------------------------------------------------------------------------
// G row = sum of 16 AAT partials. 512 blocks x 64 thr.
// ---------------------------------------------------------------------------
__global__ __launch_bounds__(64) void k_redG(const float* __restrict__ P,
                                             float* __restrict__ G) {
  const int row = blockIdx.x, lane = threadIdx.x;
#pragma unroll
  for (int j = 0; j < 2; j++) {
    const int i4 = row * 128 + lane + 64 * j;
    float4 s = ((const float4*)P)[i4];
#pragma unroll
    for (int q = 1; q < 16; q++) {
      const float4 v = ((const float4*)(P + (size_t)q * 262144))[i4];
      s.x += v.x; s.y += v.y; s.z += v.z; s.w += v.w;
    }
    ((float4*)G)[i4] = s;
  }
}

// ---------------------------------------------------------------------------
// X0 = c0 I + c1 G + c2 G^2 : degree-2 Chebyshev p(lambda) ~ 1/lambda on
// [0.35, 2.0]. r = T3(x)/T3(m), m=1.4242424, T3(m)=7.2833752, E0=0.13730.
// c0 = s(12m^2-3)/T3(m), c1 = -12 m s^2/T3(m), c2 = 4 s^3/T3(m), s=1.2121212.
// G^2 partials come from k_ns_a(G,G,P). 256 blocks x 256 thr. [R14(b)]
// ---------------------------------------------------------------------------
__global__ void k_init2s(float* __restrict__ X, const float* __restrict__ G,
                         const float* __restrict__ P, int* __restrict__ flag) {
  const float c0 = 3.5517450f;
  const float c1 = -3.4476528f;
  const float c2 = 0.9780600f;
  const int i4 = blockIdx.x * 256 + threadIdx.x;  // 0..65535
  float4 s = ((const float4*)P)[i4];
#pragma unroll
  for (int q = 1; q < 4; q++) {
    const float4 v = ((const float4*)(P + (size_t)q * 262144))[i4];
    s.x += v.x; s.y += v.y; s.z += v.z; s.w += v.w;
  }
  const float4 g4 = ((const float4*)G)[i4];
  const int e0 = i4 * 4;
  const int row = e0 >> 9, cb = e0 & 511;
  float4 xv;
  xv.x = c2 * s.x + c1 * g4.x + ((cb + 0) == row ? c0 : 0.f);
  xv.y = c2 * s.y + c1 * g4.y + ((cb + 1) == row ? c0 : 0.f);
  xv.z = c2 * s.z + c1 * g4.z + ((cb + 2) == row ? c0 : 0.f);
  xv.w = c2 * s.w + c1 * g4.w + ((cb + 3) == row ? c0 : 0.f);
  ((float4*)X)[i4] = xv;
  if (i4 == 0) { flag[0] = 0; flag[1] = 0; }
}

// ---------------------------------------------------------------------------
// NS (a): P[0..3] = G * Xc partials. grid (8,8,4), K-slice 128, 256 thr.
// (Also reused as the G^2 partial GEMM with Xc = G.)
// ---------------------------------------------------------------------------
__global__ __launch_bounds__(256) void k_ns_a(const float* __restrict__ G,
                                              const float* __restrict__ Xc,
                                              float* __restrict__ P) {
  __shared__ float At[2][32][68];
  __shared__ float Bt[2][32][68];
  const int tid = threadIdx.x;
  const int tx = tid & 15, ty = tid >> 4;
  const int bj = blockIdx.x * 64, bi = blockIdx.y * 64;
  const int Kb = blockIdx.z * 128;
  const int ar = tid >> 3, ak = tid & 7;
  const int br = tid >> 4, bc = tid & 15;
  const int ak4 = ak * 4, ty4 = ty * 4, tx4 = tx * 4, bc4 = bc * 4;
  const float* pa0 = &G[(size_t)(bi + ar) * Mrows + Kb + ak4];
  const float* pa1 = pa0 + (size_t)32 * Mrows;
  const float* pb0 = &Xc[(size_t)(Kb + br) * Mrows + bj + bc4];
  const float* pb1 = pb0 + (size_t)16 * Mrows;
  float4 ra0 = *(const float4*)pa0, ra1 = *(const float4*)pa1;
  float4 rb0 = *(const float4*)pb0, rb1 = *(const float4*)pb1;
  float c0x = 0.f, c0y = 0.f, c0z = 0.f, c0w = 0.f;
  float c1x = 0.f, c1y = 0.f, c1z = 0.f, c1w = 0.f;
  float c2x = 0.f, c2y = 0.f, c2z = 0.f, c2w = 0.f;
  float c3x = 0.f, c3y = 0.f, c3z = 0.f, c3w = 0.f;
  for (int s = 0; s < 4; ++s) {
    float (*Atc)[68] = At[s & 1];
    float (*Btc)[68] = Bt[s & 1];
    Atc[ak4 + 0][ar] = ra0.x; Atc[ak4 + 1][ar] = ra0.y;
    Atc[ak4 + 2][ar] = ra0.z; Atc[ak4 + 3][ar] = ra0.w;
    Atc[ak4 + 0][ar + 32] = ra1.x; Atc[ak4 + 1][ar + 32] = ra1.y;
    Atc[ak4 + 2][ar + 32] = ra1.z; Atc[ak4 + 3][ar + 32] = ra1.w;
    *(float4*)&Btc[br][bc4]      = rb0;
    *(float4*)&Btc[br + 16][bc4] = rb1;
    __syncthreads();
    if (s < 3) {
      const int offA = (s + 1) * 32;
      const size_t offB = (size_t)(s + 1) * 32 * Mrows;
      ra0 = *(const float4*)(pa0 + offA); ra1 = *(const float4*)(pa1 + offA);
      rb0 = *(const float4*)(pb0 + offB); rb1 = *(const float4*)(pb1 + offB);
    }
#pragma unroll
    for (int kk = 0; kk < 32; kk++) {
      float4 a = *(float4*)&Atc[kk][ty4];
      float4 b = *(float4*)&Btc[kk][tx4];
      c0x += a.x * b.x; c0y += a.x * b.y; c0z += a.x * b.z; c0w += a.x * b.w;
      c1x += a.y * b.x; c1y += a.y * b.y; c1z += a.y * b.z; c1w += a.y * b.w;
      c2x += a.z * b.x; c2y += a.z * b.y; c2z += a.z * b.z; c2w += a.z * b.w;
      c3x += a.w * b.x; c3y += a.w * b.y; c3z += a.w * b.z; c3w += a.w * b.w;
    }
  }
  float* Co = P + (size_t)blockIdx.z * 262144;
  size_t o = (size_t)(bi + ty4) * Mrows + bj + tx4;
  *(float4*)&Co[o]             = make_float4(c0x, c0y, c0z, c0w);
  *(float4*)&Co[o + Mrows]     = make_float4(c1x, c1y, c1z, c1w);
  *(float4*)&Co[o + 2 * Mrows] = make_float4(c2x, c2y, c2z, c2w);
  *(float4*)&Co[o + 3 * Mrows] = make_float4(c3x, c3y, c3z, c3w);
}

// ---------------------------------------------------------------------------
// NS (b): P[4..7] = Xc * T partials, T = sum(P[0..3]) folded into B-staging.
// grid (8,8,4). [fold logic proven in R7 coop phase (b)]
// ---------------------------------------------------------------------------
__global__ __launch_bounds__(256) void k_ns_b(const float* __restrict__ Xc,
                                              const float* __restrict__ P,
                                              float* __restrict__ Pout) {
  __shared__ float At[32][68];
  __shared__ float Bt[32][68];
  const int tid = threadIdx.x;
  const int tx = tid & 15, ty = tid >> 4;
  const int bj = blockIdx.x * 64, bi = blockIdx.y * 64;
  const int Kb = blockIdx.z * 128;
  float c0x = 0.f, c0y = 0.f, c0z = 0.f, c0w = 0.f;
  float c1x = 0.f, c1y = 0.f, c1z = 0.f, c1w = 0.f;
  float c2x = 0.f, c2y = 0.f, c2z = 0.f, c2w = 0.f;
  float c3x = 0.f, c3y = 0.f, c3z = 0.f, c3w = 0.f;
  for (int k0 = 0; k0 < 128; k0 += 32) {
#pragma unroll
    for (int l = 0; l < 2; l++) {
      int f = tid + l * 256;
      int ar = f >> 3, ak = f & 7;
      const float4 av = *(const float4*)&Xc[(size_t)(bi + ar) * Mrows + Kb + k0 + ak * 4];
      At[ak * 4 + 0][ar] = av.x; At[ak * 4 + 1][ar] = av.y;
      At[ak * 4 + 2][ar] = av.z; At[ak * 4 + 3][ar] = av.w;
      int br = f >> 4, bc = f & 15;
      const size_t bo = (size_t)(Kb + k0 + br) * Mrows + bj + bc * 4;
      float4 bs = *(const float4*)&P[bo];
#pragma unroll
      for (int q = 1; q < 4; q++) {
        const float4 v = *(const float4*)&P[bo + (size_t)q * 262144];
        bs.x += v.x; bs.y += v.y; bs.z += v.z; bs.w += v.w;
      }
      *(float4*)&Bt[br][bc * 4] = bs;
    }
    __syncthreads();
#pragma unroll
    for (int kk = 0; kk < 32; kk++) {
      float4 a = *(float4*)&At[kk][ty * 4];
      float4 b = *(float4*)&Bt[kk][tx * 4];
      c0x += a.x * b.x; c0y += a.x * b.y; c0z += a.x * b.z; c0w += a.x * b.w;
      c1x += a.y * b.x; c1y += a.y * b.y; c1z += a.y * b.z; c1w += a.y * b.w;
      c2x += a.z * b.x; c2y += a.z * b.y; c2z += a.z * b.z; c2w += a.z * b.w;
      c3x += a.w * b.x; c3y += a.w * b.y; c3z += a.w * b.z; c3w += a.w * b.w;
    }
    __syncthreads();
  }
  float* Co = Pout + (size_t)blockIdx.z * 262144;
  size_t o = (size_t)(bi + ty * 4) * Mrows + bj + tx * 4;
  *(float4*)&Co[o]             = make_float4(c0x, c0y, c0z, c0w);
  *(float4*)&Co[o + Mrows]     = make_float4(c1x, c1y, c1z, c1w);
  *(float4*)&Co[o + 2 * Mrows] = make_float4(c2x, c2y, c2z, c2w);
  *(float4*)&Co[o + 3 * Mrows] = make_float4(c3x, c3y, c3z, c3w);
}

// NS (c): Xn = 2*Xc - sum(P[4..7]). 256 blocks x 256 thr (float4 each).
__global__ void k_ns_c(const float* __restrict__ Xc, const float* __restrict__ P,
                       float* __restrict__ Xn) {
  const int i4 = blockIdx.x * 256 + threadIdx.x;
  float4 s = ((const float4*)(P + (size_t)4 * 262144))[i4];
#pragma unroll
  for (int q = 5; q < 8; q++) {
    const float4 v = ((const float4*)(P + (size_t)q * 262144))[i4];
    s.x += v.x; s.y += v.y; s.z += v.z; s.w += v.w;
  }
  const float4 xc = ((const float4*)Xc)[i4];
  ((float4*)Xn)[i4] = make_float4(2.f * xc.x - s.x, 2.f * xc.y - s.y,
                                  2.f * xc.z - s.z, 2.f * xc.w - s.w);
}

// ---------------------------------------------------------------------------
// fp64 512x512 GEMMs for R = X (I + E + E^2) => G R = I - E^3.
// ---------------------------------------------------------------------------
__global__ __launch_bounds__(256) void k_gemm_E(const float* __restrict__ G,
                                                const float* __restrict__ X,
                                                double* __restrict__ E) {
  __shared__ float Gs[32][33], Xs[32][33];
  const int tid = threadIdx.x;
  const int tx = tid & 15, ty = tid >> 4;
  const int bi = blockIdx.y * 32, bj = blockIdx.x * 32;
  const int r0 = ty * 2, c0 = tx * 2;
  double a00 = 0, a01 = 0, a10 = 0, a11 = 0;
  for (int k0 = 0; k0 < Mrows; k0 += 32) {
#pragma unroll
    for (int l = 0; l < 4; l++) {
      int e = tid + l * 256;
      int rr = e >> 5, cc = e & 31;
      Gs[rr][cc] = G[(size_t)(bi + rr) * Mrows + k0 + cc];
      Xs[rr][cc] = X[(size_t)(k0 + rr) * Mrows + bj + cc];
    }
    __syncthreads();
#pragma unroll
    for (int kk = 0; kk < 32; kk++) {
      double g0 = Gs[r0][kk], g1 = Gs[r0 + 1][kk];
      double x0 = Xs[kk][c0], x1 = Xs[kk][c0 + 1];
      a00 += g0 * x0; a01 += g0 * x1; a10 += g1 * x0; a11 += g1 * x1;
    }
    __syncthreads();
  }
  size_t o = (size_t)(bi + r0) * Mrows + bj + c0;
  E[o] = ((bi + r0) == (bj + c0) ? 1.0 : 0.0) - a00;
  E[o + 1] = ((bi + r0) == (bj + c0 + 1) ? 1.0 : 0.0) - a01;
  E[o + Mrows] = ((bi + r0 + 1) == (bj + c0) ? 1.0 : 0.0) - a10;
  E[o + Mrows + 1] = ((bi + r0 + 1) == (bj + c0 + 1) ? 1.0 : 0.0) - a11;
}

__global__ __launch_bounds__(256) void k_gemm_XE(const float* __restrict__ X,
                                                 const double* __restrict__ E,
                                                 double* __restrict__ U) {
  __shared__ float Xs[32][33];
  __shared__ double Es[32][33];
  const int tid = threadIdx.x;
  const int tx = tid & 15, ty = tid >> 4;
  const int bi = blockIdx.y * 32, bj = blockIdx.x * 32;
  const int r0 = ty * 2, c0 = tx * 2;
  double a00 = 0, a01 = 0, a10 = 0, a11 = 0;
  for (int k0 = 0; k0 < Mrows; k0 += 32) {
#pragma unroll
    for (int l = 0; l < 4; l++) {
      int e = tid + l * 256;
      int rr = e >> 5, cc = e & 31;
      Xs[rr][cc] = X[(size_t)(bi + rr) * Mrows + k0 + cc];
      Es[rr][cc] = E[(size_t)(k0 + rr) * Mrows + bj + cc];
    }
    __syncthreads();
#pragma unroll
    for (int kk = 0; kk < 32; kk++) {
      double x0 = Xs[r0][kk], x1 = Xs[r0 + 1][kk];
      double e0 = Es[kk][c0], e1 = Es[kk][c0 + 1];
      a00 += x0 * e0; a01 += x0 * e1; a10 += x1 * e0; a11 += x1 * e1;
    }
    __syncthreads();
  }
  size_t o = (size_t)(bi + r0) * Mrows + bj + c0;
  U[o] = a00; U[o + 1] = a01; U[o + Mrows] = a10; U[o + Mrows + 1] = a11;
}

// R = X + U + U*E  (fp64)  => R = X (I + E + E^2)
__global__ __launch_bounds__(256) void k_gemm_UER(const double* __restrict__ U,
                                                  const double* __restrict__ E,
                                                  const float* __restrict__ Xf,
                                                  double* __restrict__ R) {
  __shared__ double Us[32][33];
  __shared__ double Es[32][33];
  const int tid = threadIdx.x;
  const int tx = tid & 15, ty = tid >> 4;
  const int bi = blockIdx.y * 32, bj = blockIdx.x * 32;
  const int r0 = ty * 2, c0 = tx * 2;
  double a00 = 0, a01 = 0, a10 = 0, a11 = 0;
  for (int k0 = 0; k0 < Mrows; k0 += 32) {
#pragma unroll
    for (int l = 0; l < 4; l++) {
      int e = tid + l * 256;
      int rr = e >> 5, cc = e & 31;
      Us[rr][cc] = U[(size_t)(bi + rr) * Mrows + k0 + cc];
      Es[rr][cc] = E[(size_t)(k0 + rr) * Mrows + bj + cc];
    }
    __syncthreads();
#pragma unroll
    for (int kk = 0; kk < 32; kk++) {
      double u0 = Us[r0][kk], u1 = Us[r0 + 1][kk];
      double e0 = Es[kk][c0], e1 = Es[kk][c0 + 1];
      a00 += u0 * e0; a01 += u0 * e1; a10 += u1 * e0; a11 += u1 * e1;
    }
    __syncthreads();
  }
  size_t o = (size_t)(bi + r0) * Mrows + bj + c0;
  R[o]     = (double)Xf[o] + U[o] + a00;
  R[o + 1] = (double)Xf[o + 1] + U[o + 1] + a01;
  R[o + Mrows] = (double)Xf[o + Mrows] + U[o + Mrows] + a10;
  R[o + Mrows + 1] = (double)Xf[o + Mrows + 1] + U[o + Mrows + 1] + a11;
}

// y = R * rhs (fp64 matvec, 512 blocks x 64 thr). [proven R6]
__global__ __launch_bounds__(64) void k_solveR(const double* __restrict__ R,
                                               const float* __restrict__ rhs_f,
                                               const double* __restrict__ rhs_d,
                                               double* __restrict__ y,
                                               const int* __restrict__ flag, int chk) {
  if (chk && *flag) return;
  const int m = blockIdx.x, t = threadIdx.x;
  const double2* Rr = (const double2*)(R + (size_t)m * Mrows);
  double acc = 0.0;
#pragma unroll
  for (int i = 0; i < 4; i++) {
    int i2 = t + 64 * i;
    double2 a = Rr[i2];
    double x0, x1;
    if (rhs_f) { x0 = rhs_f[i2 * 2]; x1 = rhs_f[i2 * 2 + 1]; }
    else       { x0 = rhs_d[i2 * 2]; x1 = rhs_d[i2 * 2 + 1]; }
    acc += a.x * x0 + a.y * x1;
  }
  acc = wredD(acc);
  if (t == 0) y[m] = acc;
}

// t1d[m] = fp64 dot(A[m,:], v), 512 blocks x 256. [proven R6]
__global__ __launch_bounds__(256) void k_mv_A(const float* __restrict__ Mat,
                                              const float* __restrict__ v,
                                              double* __restrict__ t1d,
                                              const int* __restrict__ flag, int chk) {
  if (chk && *flag) return;
  const int m = blockIdx.x, tid = threadIdx.x;
  const float4* Mr = (const float4*)(Mat + (size_t)m * Ncols);
  const float4* v4 = (const float4*)v;
  double acc = 0.0;
#pragma unroll
  for (int i = 0; i < 4; i++) {
    float4 a = Mr[tid + 256 * i];
    float4 x = v4[tid + 256 * i];
    acc += (double)a.x * x.x + (double)a.y * x.y + (double)a.z * x.z + (double)a.w * x.w;
  }
  __shared__ double sb[4];
  acc = wredD(acc);
  const int lane = tid & 63, wid = tid >> 6;
  if (!lane) sb[wid] = acc;
  __syncthreads();
  if (!tid) t1d[m] = sb[0] + sb[1] + sb[2] + sb[3];
}

// ---------------------------------------------------------------------------
// Bp = B p with the PREVIOUS iteration's CG update fused in (R11).
// 1024 blocks x 256 thr, 4 rows/block. When upd=1: every block replicates the
// k_vup scalar reduce from dotbuf (bitwise-identical order), computes p_new
// into its own LDS; blocks 0..15 write disjoint slices of p_cur/r_cur/dv.
// Ping-pong p/r buffers: readers only touch *_prev, writers only *_cur.
// ---------------------------------------------------------------------------
__global__ __launch_bounds__(256) void k_mv_B4u(const float* __restrict__ B,
                                                const float* __restrict__ p_prev,
                                                float* __restrict__ p_cur,
                                                const float* __restrict__ r_prev,
                                                float* __restrict__ r_cur,
                                                const float* __restrict__ PBp,
                                                const double* __restrict__ dotbuf,
                                                float* __restrict__ dv,
                                                float* __restrict__ Bp,
                                                int* __restrict__ flag, int upd) {
  if (flag[0]) return;
  __shared__ float4 ps[1024];
  __shared__ double sdd[20];
  const int tid = threadIdx.x;
  const int wid = tid >> 6, lane = tid & 63;
  if (!upd) {
#pragma unroll
    for (int l = 0; l < 4; l++)
      ps[tid + 256 * l] = ((const float4*)p_cur)[tid + 256 * l];
  } else {
#pragma unroll
    for (int d = 0; d < 5; d++) {
      double v = dotbuf[d * 256 + tid];
      v = wredD(v);
      if (!lane) sdd[d * 4 + wid] = v;
    }
    __syncthreads();
    double tot[5];
#pragma unroll
    for (int d = 0; d < 5; d++)
      tot[d] = sdd[d * 4] + sdd[d * 4 + 1] + sdd[d * 4 + 2] + sdd[d * 4 + 3];
    const double pPBp = tot[0], pp = tot[1], rPBp = tot[2], PBp2 = tot[3], rr = tot[4];
    if (pPBp <= 1e-6 * pp) { if (tid == 0) flag[0] = 1; return; }
    const double alpha = rr / fmax(pPBp, 1e-300);
    double rn2 = rr - 2.0 * alpha * rPBp + alpha * alpha * PBp2;
    rn2 = fmax(rn2, 0.0);
    const double beta = rn2 / fmax(rr, 1e-300);
    const bool wb = (blockIdx.x < 16);
#pragma unroll
    for (int l = 0; l < 4; l++) {
      const int i4 = tid + 256 * l;
      const float4 pv = ((const float4*)p_prev)[i4];
      const float4 rv = ((const float4*)r_prev)[i4];
      const float4 qv = ((const float4*)PBp)[i4];
      const double rd0 = (double)rv.x - alpha * (double)qv.x;
      const double rd1 = (double)rv.y - alpha * (double)qv.y;
      const double rd2 = (double)rv.z - alpha * (double)qv.z;
      const double rd3 = (double)rv.w - alpha * (double)qv.w;
      const float4 pn = make_float4((float)(rd0 + beta * (double)pv.x),
                                    (float)(rd1 + beta * (double)pv.y),
                                    (float)(rd2 + beta * (double)pv.z),
                                    (float)(rd3 + beta * (double)pv.w));
      ps[i4] = pn;
      if (wb && (i4 >> 6) == (int)blockIdx.x) {
        ((float4*)p_cur)[i4] = pn;
        ((float4*)r_cur)[i4] =
            make_float4((float)rd0, (float)rd1, (float)rd2, (float)rd3);
        float4 dvv = ((float4*)dv)[i4];
        dvv.x = (float)((double)dvv.x + alpha * (double)pv.x);
        dvv.y = (float)((double)dvv.y + alpha * (double)pv.y);
        dvv.z = (float)((double)dvv.z + alpha * (double)pv.z);
        dvv.w = (float)((double)dvv.w + alpha * (double)pv.w);
        ((float4*)dv)[i4] = dvv;
      }
    }
    if (rn2 < 1e-16) {  // converged: updates written, skip this matvec
      if (tid == 0 && blockIdx.x == 0) flag[0] = 1;
      return;
    }
  }
  __syncthreads();
  const int row = blockIdx.x * 4 + wid;
  const float4* Br = (const float4*)(B + (size_t)row * Ncols);
  double acc = 0.0;
#pragma unroll
  for (int i = 0; i < 16; i++) {
    const float4 a = Br[lane + 64 * i];
    const float4 x = ps[lane + 64 * i];
    acc += (double)a.x * x.x + (double)a.y * x.y + (double)a.z * x.z + (double)a.w * x.w;
  }
  acc = wredD(acc);
  if (!lane) Bp[row] = (float)acc;
}

// Setup outputs + CG init. [proven R6]
__global__ __launch_bounds__(256) void k_setup_fin(const float* __restrict__ A,
                                                   const double* __restrict__ y0d,
                                                   const double* __restrict__ y1d,
                                                   const float* __restrict__ g,
                                                   float* __restrict__ out,
                                                   float* __restrict__ r,
                                                   float* __restrict__ p,
                                                   float* __restrict__ dv) {
  __shared__ double y0s[512], y1s[512];
  const int tid = threadIdx.x;
  y0s[tid] = y0d[tid]; y0s[tid + 256] = y0d[tid + 256];
  y1s[tid] = y1d[tid]; y1s[tid + 256] = y1d[tid + 256];
  __syncthreads();
  const int col = blockIdx.x * 256 + tid;
  double xa = 0.0, ra = 0.0;
  for (int m = 0; m < Mrows; m++) {
    double av = (double)A[(size_t)m * Ncols + col];
    xa += av * y0s[m];
    ra += av * y1s[m];
  }
  out[col] = (float)xa;
  float rv = (float)(ra - (double)g[col]);
  r[col] = rv; p[col] = rv; dv[col] = 0.f;
}

// ---------------------------------------------------------------------------
// PBp = Bp - A^T y ; fresh fp64 dots {p.PBp, p.p, r.PBp, PBp.PBp, r.r}
// -> dotbuf[d*256 + bid]. 256 blocks x 256 thr, 16 cols/block, m 16-split.
// ---------------------------------------------------------------------------
__global__ __launch_bounds__(256) void k_pcc3(const float* __restrict__ A,
                                              const double* __restrict__ yd,
                                              const float* __restrict__ Bp,
                                              const float* __restrict__ p,
                                              const float* __restrict__ r,
                                              float* __restrict__ PBp,
                                              double* __restrict__ dotbuf,
                                              const int* __restrict__ flag) {
  if (*flag) return;
  __shared__ double ysh[512];
  __shared__ double part[256];
  __shared__ double d5[80];
  const int tid = threadIdx.x;
  ysh[tid] = yd[tid]; ysh[tid + 256] = yd[tid + 256];
  __syncthreads();
  const int cl = tid & 15, ms = tid >> 4;
  const int col = blockIdx.x * 16 + cl;
  double acc = 0.0;
  for (int m = ms * 32; m < ms * 32 + 32; m++)
    acc += (double)A[(size_t)m * Ncols + col] * ysh[m];
  part[ms * 16 + cl] = acc;
  __syncthreads();
  if (tid < 16) {
    const int c = blockIdx.x * 16 + tid;
    double s = 0.0;
#pragma unroll
    for (int q = 0; q < 16; q++) s += part[q * 16 + tid];
    const double pb = (double)Bp[c] - s;
    PBp[c] = (float)pb;
    const double pi = (double)p[c];
    const double ri = (double)r[c];
    d5[0 * 16 + tid] = pi * pb;
    d5[1 * 16 + tid] = pi * pi;
    d5[2 * 16 + tid] = ri * pb;
    d5[3 * 16 + tid] = pb * pb;
    d5[4 * 16 + tid] = ri * ri;
  }
  __syncthreads();
  if (tid < 5) {
    double s = 0.0;
#pragma unroll
    for (int c = 0; c < 16; c++) s += d5[tid * 16 + c];
    dotbuf[tid * 256 + blockIdx.x] = s;
  }
}

// Final dv update for the LAST CG iteration (16 blocks x 256).
__global__ __launch_bounds__(256) void k_vup_fin(float* __restrict__ dv,
                                                 const float* __restrict__ p_last,
                                                 const double* __restrict__ dotbuf,
                                                 const int* __restrict__ flag) {
  if (*flag) return;
  __shared__ double sdd[20];
  const int tid = threadIdx.x;
  const int wid = tid >> 6, lane = tid & 63;
#pragma unroll
  for (int d = 0; d < 5; d++) {
    double v = dotbuf[d * 256 + tid];
    v = wredD(v);
    if (!lane) sdd[d * 4 + wid] = v;
  }
  __syncthreads();
  double tot[5];
#pragma unroll
  for (int d = 0; d < 5; d++)
    tot[d] = sdd[d * 4] + sdd[d * 4 + 1] + sdd[d * 4 + 2] + sdd[d * 4 + 3];
  const double pPBp = tot[0], pp = tot[1], rr = tot[4];
  if (pPBp <= 1e-6 * pp) return;   // bad curvature: no update (matches k_vup)
  const double alpha = rr / fmax(pPBp, 1e-300);
  const int idx = blockIdx.x * 256 + tid;
  dv[idx] = (float)((double)dv[idx] + alpha * (double)p_last[idx]);
}

// out[4096+col] = dv[col] - (A^T yd)[col]. [proven R6]
__global__ __launch_bounds__(256) void k_final_d(const float* __restrict__ A,
                                                 const double* __restrict__ yd,
                                                 const float* __restrict__ dv,
                                                 float* __restrict__ out) {
  __shared__ double ysm[512];
  const int tid = threadIdx.x;
  ysm[tid] = yd[tid]; ysm[tid + 256] = yd[tid + 256];
  __syncthreads();
  const int col = blockIdx.x * 256 + tid;
  double acc = 0.0;
  for (int m = 0; m < Mrows; m++) acc += (double)A[(size_t)m * Ncols + col] * ysm[m];
  out[Ncols + col] = (float)((double)dv[col] - acc);
}

// ---------------------------------------------------------------------------
extern "C" void kernel_launch(void* const* d_in, const int* in_sizes, int n_in,
                              void* d_out, int out_size, void* d_ws, size_t ws_size,
                              hipStream_t stream) {
  const float* A = (const float*)d_in[0];   // 512 x 4096
  const float* b = (const float*)d_in[1];   // 512
  const float* B = (const float*)d_in[2];   // 4096 x 4096
  const float* g = (const float*)d_in[3];   // 4096
  float* out = (float*)d_out;               // x[4096] then d[4096]
  float* ws = (float*)d_ws;

  // NOTE aliasing is ordering-safe: aat writes P[0..15] (ws+1048576 ..
  // ws+5242880) FIRST; redG consumes; all later buffers in that range
  // (Ed/Ud/Rd, CG vectors, dotbuf, flag, p2/r2) are written after.
  float*  G   = ws;                         // 262144 floats
  float*  Xa  = ws + 262144;
  float*  Xb  = ws + 524288;
  float*  P   = ws + 1048576;               // 16 x 262144 (AAT) / 8 (NS)
  double* Ed  = (double*)(ws + 1048576);    // aliases P (used after NS only)
  double* Ud  = (double*)(ws + 1572864);    // aliases P
  double* Rd  = (double*)(ws + 3145728);    // 512x512 fp64
  float*  Bp  = ws + 3670016;               // 4096 each
  float*  PBp = ws + 3674112;
  float*  r   = ws + 3678208;
  float*  p   = ws + 3682304;
  float*  dv  = ws + 3686400;
  double* t1d = (double*)(ws + 3690496);    // 512 doubles
  double* y0d = (double*)(ws + 3691520);
  double* y1d = (double*)(ws + 3692544);
  double* dotbuf = (double*)(ws + 3693568); // 5 x 256 doubles
  int*    flag   = (int*)(ws + 3696132);
  float*  p2  = ws + 3696144;               // ping-pong partners (R11)
  float*  r2  = ws + 3700240;

  // --- G = A A^T (16 K-slices, 128^2 tiles, 8x8/thread) ; row-reduce ---
  k_aat_part<<<dim3(4, 4, 16), 256, 0, stream>>>(A, P);
  k_redG<<<Mrows, 64, 0, stream>>>(P, G);

  // --- X0 = c0 I + c1 G + c2 G^2 (degree-2 Chebyshev, R14(b)) ---
  k_ns_a<<<dim3(8, 8, 4), 256, 0, stream>>>(G, G, P);          // P[0..3] = G*G
  k_init2s<<<256, 256, 0, stream>>>(Xa, G, P, flag);

  // --- Newton-Schulz: X' = 2X - X(GX), 2 iters (R14(b)), 3 kernels each ---
  float* Xcur = Xa;
  float* Xnxt = Xb;
  for (int it = 0; it < 2; it++) {
    k_ns_a<<<dim3(8, 8, 4), 256, 0, stream>>>(G, Xcur, P);      // P[0..3] = G*X
    k_ns_b<<<dim3(8, 8, 4), 256, 0, stream>>>(Xcur, P, P + 4 * 262144);  // P[4..7] = X*T
    k_ns_c<<<256, 256, 0, stream>>>(Xcur, P, Xnxt);             // Xn = 2X - sum
    float* tmp = Xcur; Xcur = Xnxt; Xnxt = tmp;
  }

  // --- R = X (I+E+E^2), E = I - G X : G*R = I - E^3 (fp64) ---
  k_gemm_E<<<dim3(16, 16), 256, 0, stream>>>(G, Xcur, Ed);
  k_gemm_XE<<<dim3(16, 16), 256, 0, stream>>>(Xcur, Ed, Ud);
  k_gemm_UER<<<dim3(16, 16), 256, 0, stream>>>(Ud, Ed, Xcur, Rd);

  // --- x = A^T R b ; r0 = p = A^T R (A g) - g ---
  k_mv_A<<<Mrows, 256, 0, stream>>>(A, g, t1d, flag, 0);
  k_solveR<<<Mrows, 64, 0, stream>>>(Rd, b, (const double*)0, y0d, flag, 0);
  k_solveR<<<Mrows, 64, 0, stream>>>(Rd, (const float*)0, t1d, y1d, flag, 0);
  k_setup_fin<<<16, 256, 0, stream>>>(A, y0d, y1d, g, out, r, p, dv);

  // --- projected CG, CG_ITERS iterations, 4 launches/iter ---
  float* pb[2] = {p, p2};
  float* rb[2] = {r, r2};
  for (int it = 0; it < CG_ITERS; it++) {
    const int cur = it & 1, prv = cur ^ 1;
    if (it == 0)
      k_mv_B4u<<<1024, 256, 0, stream>>>(B, pb[0], pb[0], rb[0], rb[0], PBp,
                                         dotbuf, dv, Bp, flag, 0);
    else
      k_mv_B4u<<<1024, 256, 0, stream>>>(B, pb[prv], pb[cur], rb[prv], rb[cur],
                                         PBp, dotbuf, dv, Bp, flag, 1);
    k_mv_A<<<Mrows, 256, 0, stream>>>(A, Bp, t1d, flag, 1);
    k_solveR<<<Mrows, 64, 0, stream>>>(Rd, (const float*)0, t1d, y1d, flag, 1);
    k_pcc3<<<256, 256, 0, stream>>>(A, y1d, Bp, pb[cur], rb[cur], PBp, dotbuf, flag);
  }
  k_vup_fin<<<16, 256, 0, stream>>>(dv, pb[(CG_ITERS - 1) & 1], dotbuf, flag);

  // --- d_out = P(dv): strip row-space contamination ---
  k_mv_A<<<Mrows, 256, 0, stream>>>(A, dv, t1d, flag, 0);
  k_solveR<<<Mrows, 64, 0, stream>>>(Rd, (const float*)0, t1d, y1d, flag, 0);
  k_final_d<<<16, 256, 0, stream>>>(A, y1d, dv, out);
}

// Round 7
// 465.939 us; speedup vs baseline: 1.0786x; 1.0786x over previous
//
#include <hip/hip_runtime.h>
#include <hip/hip_bf16.h>

// ProjectedCGCraig on MI355X (gfx950).
//   x = A^T G^{-1} b,  G = A A^T (512x512)
//   d = projected CG with P v = v - A^T G^{-1} A v
// LESSON (R3): per-iteration projection must be refinement-exact (<=1e-9).
// LESSON (R5): CG scalars MEASURED fresh from stored fp32 vectors each iter.
// LESSON (R7): grid.sync() ~28us; launches (~2.2us) are the cheap grid sync.
// LESSON (R9->R10): LAST-BLOCK-ticket fold REGRESSED ~+100us. Launch
//   boundary IS the cheap handoff.
// LESSON (R14->R15): LDS row pad must keep rows 16B-ALIGNED. Pad 130 floats
//   (520B = 8 mod 16) forced ds_read_b64 fallback -> 2x LDS instr -> aat
//   83us (=2x41, exact). Pad 132 (528B = 33x16) restores ds_read_b128.
//   Also: 1 block/CU = 1 wave/SIMD (R14's z=16) leaves NO TLP to hide
//   ds_read latency -> z=32 gives 2 blocks/CU (2 waves/SIMD).
// R11: CG fused update (k_mv_B4u replicated-reduce, ping-pong p/r).
// R12/R13: Chebyshev init on FIXED MP interval [0.35,2.0]; CG=5; cubic refine.
// R14(b) kept: degree-2 Chebyshev init X0 = c0 I + c1 G + c2 G^2, NS=2.
// R15 (this round): aat 8x8 micro-tile FIXED: pad 132 + z=32.
//   Per-CU LDS pipe: 4096 ds_read_b128 x 12cyc + writes ~ 24.5K cyc -> ~28us.
// M=512, N=4096 fixed.

#define Mrows 512
#define Ncols 4096
#define CG_ITERS 5
#define AAT_PAD 132

__device__ __forceinline__ float wredF(float v) {
#pragma unroll
  for (int off = 32; off; off >>= 1) v += __shfl_down(v, off, 64);
  return v;
}
__device__ __forceinline__ double wredD(double v) {
#pragma unroll
  for (int off = 32; off; off >>= 1) v += __shfl_down(v, off, 64);
  return v;
}

// ---------------------------------------------------------------------------
// Partial AAT: slice bz = A[bi..+128][Kb..+128] * A[bj..+128][..]^T.
// grid (4,4,32), 256 thr, 8x8 micro-tile as 2x2 float4 groups at col/col+64.
// R15: pad 132 (16B-aligned rows -> real b128), z=32 (2 blocks/CU for TLP).
// ---------------------------------------------------------------------------
__global__ __launch_bounds__(256) void k_aat_part(const float* __restrict__ A,
                                                  float* __restrict__ P) {
  __shared__ __align__(16) float At[2][32][AAT_PAD];
  __shared__ __align__(16) float Bt[2][32][AAT_PAD];
  const int tid = threadIdx.x;
  const int tx = tid & 15, ty = tid >> 4;
  const int bj = blockIdx.x * 128, bi = blockIdx.y * 128;
  const int Kb = blockIdx.z * 128;
  const int ar = tid >> 3, ak = tid & 7;   // staging: row ar+32l, K-offset ak*4
  const int ak4 = ak * 4, ty4 = ty * 4, tx4 = tx * 4;
  const float* pa0 = &A[(size_t)(bi + ar) * Ncols + Kb + ak4];
  const float* pa1 = pa0 + (size_t)32 * Ncols;
  const float* pa2 = pa0 + (size_t)64 * Ncols;
  const float* pa3 = pa0 + (size_t)96 * Ncols;
  const float* pb0 = &A[(size_t)(bj + ar) * Ncols + Kb + ak4];
  const float* pb1 = pb0 + (size_t)32 * Ncols;
  const float* pb2 = pb0 + (size_t)64 * Ncols;
  const float* pb3 = pb0 + (size_t)96 * Ncols;
  float4 ra0 = *(const float4*)pa0, ra1 = *(const float4*)pa1;
  float4 ra2 = *(const float4*)pa2, ra3 = *(const float4*)pa3;
  float4 rb0 = *(const float4*)pb0, rb1 = *(const float4*)pb1;
  float4 rb2 = *(const float4*)pb2, rb3 = *(const float4*)pb3;
  float4 c[8][2];
#pragma unroll
  for (int i = 0; i < 8; i++) {
    c[i][0] = make_float4(0.f, 0.f, 0.f, 0.f);
    c[i][1] = make_float4(0.f, 0.f, 0.f, 0.f);
  }
  for (int s = 0; s < 4; ++s) {
    float (*Atc)[AAT_PAD] = At[s & 1];
    float (*Btc)[AAT_PAD] = Bt[s & 1];
    Atc[ak4 + 0][ar] = ra0.x; Atc[ak4 + 1][ar] = ra0.y;
    Atc[ak4 + 2][ar] = ra0.z; Atc[ak4 + 3][ar] = ra0.w;
    Atc[ak4 + 0][ar + 32] = ra1.x; Atc[ak4 + 1][ar + 32] = ra1.y;
    Atc[ak4 + 2][ar + 32] = ra1.z; Atc[ak4 + 3][ar + 32] = ra1.w;
    Atc[ak4 + 0][ar + 64] = ra2.x; Atc[ak4 + 1][ar + 64] = ra2.y;
    Atc[ak4 + 2][ar + 64] = ra2.z; Atc[ak4 + 3][ar + 64] = ra2.w;
    Atc[ak4 + 0][ar + 96] = ra3.x; Atc[ak4 + 1][ar + 96] = ra3.y;
    Atc[ak4 + 2][ar + 96] = ra3.z; Atc[ak4 + 3][ar + 96] = ra3.w;
    Btc[ak4 + 0][ar] = rb0.x; Btc[ak4 + 1][ar] = rb0.y;
    Btc[ak4 + 2][ar] = rb0.z; Btc[ak4 + 3][ar] = rb0.w;
    Btc[ak4 + 0][ar + 32] = rb1.x; Btc[ak4 + 1][ar + 32] = rb1.y;
    Btc[ak4 + 2][ar + 32] = rb1.z; Btc[ak4 + 3][ar + 32] = rb1.w;
    Btc[ak4 + 0][ar + 64] = rb2.x; Btc[ak4 + 1][ar + 64] = rb2.y;
    Btc[ak4 + 2][ar + 64] = rb2.z; Btc[ak4 + 3][ar + 64] = rb2.w;
    Btc[ak4 + 0][ar + 96] = rb3.x; Btc[ak4 + 1][ar + 96] = rb3.y;
    Btc[ak4 + 2][ar + 96] = rb3.z; Btc[ak4 + 3][ar + 96] = rb3.w;
    __syncthreads();
    if (s < 3) {
      const int off = (s + 1) * 32;
      ra0 = *(const float4*)(pa0 + off); ra1 = *(const float4*)(pa1 + off);
      ra2 = *(const float4*)(pa2 + off); ra3 = *(const float4*)(pa3 + off);
      rb0 = *(const float4*)(pb0 + off); rb1 = *(const float4*)(pb1 + off);
      rb2 = *(const float4*)(pb2 + off); rb3 = *(const float4*)(pb3 + off);
    }
#pragma unroll
    for (int kk = 0; kk < 32; kk++) {
      const float4 a0 = *(const float4*)&Atc[kk][ty4];
      const float4 a1 = *(const float4*)&Atc[kk][64 + ty4];
      const float4 b0 = *(const float4*)&Btc[kk][tx4];
      const float4 b1 = *(const float4*)&Btc[kk][64 + tx4];
      const float av[8] = {a0.x, a0.y, a0.z, a0.w, a1.x, a1.y, a1.z, a1.w};
#pragma unroll
      for (int i = 0; i < 8; i++) {
        c[i][0].x += av[i] * b0.x; c[i][0].y += av[i] * b0.y;
        c[i][0].z += av[i] * b0.z; c[i][0].w += av[i] * b0.w;
        c[i][1].x += av[i] * b1.x; c[i][1].y += av[i] * b1.y;
        c[i][1].z += av[i] * b1.z; c[i][1].w += av[i] * b1.w;
      }
    }
  }
  float* Co = P + (size_t)blockIdx.z * 262144;
#pragma unroll
  for (int i = 0; i < 8; i++) {
    const int row = bi + ((i < 4) ? (ty4 + i) : (64 + ty4 + (i - 4)));
    const size_t o = (size_t)row * Mrows + bj;
    *(float4*)&Co[o + tx4]      = c[i][0];
    *(float4*)&Co[o + 64 + tx4] = c[i][1];
  }
}

// ---------------------------------------------------------------------------
// G row = sum of 32 AAT partials. 512 blocks x 64 thr.
// ---------------------------------------------------------------------------
__global__ __launch_bounds__(64) void k_redG(const float* __restrict__ P,
                                             float* __restrict__ G) {
  const int row = blockIdx.x, lane = threadIdx.x;
#pragma unroll
  for (int j = 0; j < 2; j++) {
    const int i4 = row * 128 + lane + 64 * j;
    float4 s = ((const float4*)P)[i4];
#pragma unroll
    for (int q = 1; q < 32; q++) {
      const float4 v = ((const float4*)(P + (size_t)q * 262144))[i4];
      s.x += v.x; s.y += v.y; s.z += v.z; s.w += v.w;
    }
    ((float4*)G)[i4] = s;
  }
}

// ---------------------------------------------------------------------------
// X0 = c0 I + c1 G + c2 G^2 : degree-2 Chebyshev p(lambda) ~ 1/lambda on
// [0.35, 2.0]. r = T3(x)/T3(m), m=1.4242424, T3(m)=7.2833752, E0=0.13730.
// G^2 partials come from k_ns_a(G,G,P). 256 blocks x 256 thr. [R14(b)]
// ---------------------------------------------------------------------------
__global__ void k_init2s(float* __restrict__ X, const float* __restrict__ G,
                         const float* __restrict__ P, int* __restrict__ flag) {
  const float c0 = 3.5517450f;
  const float c1 = -3.4476528f;
  const float c2 = 0.9780600f;
  const int i4 = blockIdx.x * 256 + threadIdx.x;  // 0..65535
  float4 s = ((const float4*)P)[i4];
#pragma unroll
  for (int q = 1; q < 4; q++) {
    const float4 v = ((const float4*)(P + (size_t)q * 262144))[i4];
    s.x += v.x; s.y += v.y; s.z += v.z; s.w += v.w;
  }
  const float4 g4 = ((const float4*)G)[i4];
  const int e0 = i4 * 4;
  const int row = e0 >> 9, cb = e0 & 511;
  float4 xv;
  xv.x = c2 * s.x + c1 * g4.x + ((cb + 0) == row ? c0 : 0.f);
  xv.y = c2 * s.y + c1 * g4.y + ((cb + 1) == row ? c0 : 0.f);
  xv.z = c2 * s.z + c1 * g4.z + ((cb + 2) == row ? c0 : 0.f);
  xv.w = c2 * s.w + c1 * g4.w + ((cb + 3) == row ? c0 : 0.f);
  ((float4*)X)[i4] = xv;
  if (i4 == 0) { flag[0] = 0; flag[1] = 0; }
}

// ---------------------------------------------------------------------------
// NS (a): P[0..3] = G * Xc partials. grid (8,8,4), K-slice 128, 256 thr.
// (Also reused as the G^2 partial GEMM with Xc = G.)
// ---------------------------------------------------------------------------
__global__ __launch_bounds__(256) void k_ns_a(const float* __restrict__ G,
                                              const float* __restrict__ Xc,
                                              float* __restrict__ P) {
  __shared__ float At[2][32][68];
  __shared__ float Bt[2][32][68];
  const int tid = threadIdx.x;
  const int tx = tid & 15, ty = tid >> 4;
  const int bj = blockIdx.x * 64, bi = blockIdx.y * 64;
  const int Kb = blockIdx.z * 128;
  const int ar = tid >> 3, ak = tid & 7;
  const int br = tid >> 4, bc = tid & 15;
  const int ak4 = ak * 4, ty4 = ty * 4, tx4 = tx * 4, bc4 = bc * 4;
  const float* pa0 = &G[(size_t)(bi + ar) * Mrows + Kb + ak4];
  const float* pa1 = pa0 + (size_t)32 * Mrows;
  const float* pb0 = &Xc[(size_t)(Kb + br) * Mrows + bj + bc4];
  const float* pb1 = pb0 + (size_t)16 * Mrows;
  float4 ra0 = *(const float4*)pa0, ra1 = *(const float4*)pa1;
  float4 rb0 = *(const float4*)pb0, rb1 = *(const float4*)pb1;
  float c0x = 0.f, c0y = 0.f, c0z = 0.f, c0w = 0.f;
  float c1x = 0.f, c1y = 0.f, c1z = 0.f, c1w = 0.f;
  float c2x = 0.f, c2y = 0.f, c2z = 0.f, c2w = 0.f;
  float c3x = 0.f, c3y = 0.f, c3z = 0.f, c3w = 0.f;
  for (int s = 0; s < 4; ++s) {
    float (*Atc)[68] = At[s & 1];
    float (*Btc)[68] = Bt[s & 1];
    Atc[ak4 + 0][ar] = ra0.x; Atc[ak4 + 1][ar] = ra0.y;
    Atc[ak4 + 2][ar] = ra0.z; Atc[ak4 + 3][ar] = ra0.w;
    Atc[ak4 + 0][ar + 32] = ra1.x; Atc[ak4 + 1][ar + 32] = ra1.y;
    Atc[ak4 + 2][ar + 32] = ra1.z; Atc[ak4 + 3][ar + 32] = ra1.w;
    *(float4*)&Btc[br][bc4]      = rb0;
    *(float4*)&Btc[br + 16][bc4] = rb1;
    __syncthreads();
    if (s < 3) {
      const int offA = (s + 1) * 32;
      const size_t offB = (size_t)(s + 1) * 32 * Mrows;
      ra0 = *(const float4*)(pa0 + offA); ra1 = *(const float4*)(pa1 + offA);
      rb0 = *(const float4*)(pb0 + offB); rb1 = *(const float4*)(pb1 + offB);
    }
#pragma unroll
    for (int kk = 0; kk < 32; kk++) {
      float4 a = *(float4*)&Atc[kk][ty4];
      float4 b = *(float4*)&Btc[kk][tx4];
      c0x += a.x * b.x; c0y += a.x * b.y; c0z += a.x * b.z; c0w += a.x * b.w;
      c1x += a.y * b.x; c1y += a.y * b.y; c1z += a.y * b.z; c1w += a.y * b.w;
      c2x += a.z * b.x; c2y += a.z * b.y; c2z += a.z * b.z; c2w += a.z * b.w;
      c3x += a.w * b.x; c3y += a.w * b.y; c3z += a.w * b.z; c3w += a.w * b.w;
    }
  }
  float* Co = P + (size_t)blockIdx.z * 262144;
  size_t o = (size_t)(bi + ty4) * Mrows + bj + tx4;
  *(float4*)&Co[o]             = make_float4(c0x, c0y, c0z, c0w);
  *(float4*)&Co[o + Mrows]     = make_float4(c1x, c1y, c1z, c1w);
  *(float4*)&Co[o + 2 * Mrows] = make_float4(c2x, c2y, c2z, c2w);
  *(float4*)&Co[o + 3 * Mrows] = make_float4(c3x, c3y, c3z, c3w);
}

// ---------------------------------------------------------------------------
// NS (b): P[4..7] = Xc * T partials, T = sum(P[0..3]) folded into B-staging.
// grid (8,8,4). [fold logic proven in R7 coop phase (b)]
// ---------------------------------------------------------------------------
__global__ __launch_bounds__(256) void k_ns_b(const float* __restrict__ Xc,
                                              const float* __restrict__ P,
                                              float* __restrict__ Pout) {
  __shared__ float At[32][68];
  __shared__ float Bt[32][68];
  const int tid = threadIdx.x;
  const int tx = tid & 15, ty = tid >> 4;
  const int bj = blockIdx.x * 64, bi = blockIdx.y * 64;
  const int Kb = blockIdx.z * 128;
  float c0x = 0.f, c0y = 0.f, c0z = 0.f, c0w = 0.f;
  float c1x = 0.f, c1y = 0.f, c1z = 0.f, c1w = 0.f;
  float c2x = 0.f, c2y = 0.f, c2z = 0.f, c2w = 0.f;
  float c3x = 0.f, c3y = 0.f, c3z = 0.f, c3w = 0.f;
  for (int k0 = 0; k0 < 128; k0 += 32) {
#pragma unroll
    for (int l = 0; l < 2; l++) {
      int f = tid + l * 256;
      int ar = f >> 3, ak = f & 7;
      const float4 av = *(const float4*)&Xc[(size_t)(bi + ar) * Mrows + Kb + k0 + ak * 4];
      At[ak * 4 + 0][ar] = av.x; At[ak * 4 + 1][ar] = av.y;
      At[ak * 4 + 2][ar] = av.z; At[ak * 4 + 3][ar] = av.w;
      int br = f >> 4, bc = f & 15;
      const size_t bo = (size_t)(Kb + k0 + br) * Mrows + bj + bc * 4;
      float4 bs = *(const float4*)&P[bo];
#pragma unroll
      for (int q = 1; q < 4; q++) {
        const float4 v = *(const float4*)&P[bo + (size_t)q * 262144];
        bs.x += v.x; bs.y += v.y; bs.z += v.z; bs.w += v.w;
      }
      *(float4*)&Bt[br][bc * 4] = bs;
    }
    __syncthreads();
#pragma unroll
    for (int kk = 0; kk < 32; kk++) {
      float4 a = *(float4*)&At[kk][ty * 4];
      float4 b = *(float4*)&Bt[kk][tx * 4];
      c0x += a.x * b.x; c0y += a.x * b.y; c0z += a.x * b.z; c0w += a.x * b.w;
      c1x += a.y * b.x; c1y += a.y * b.y; c1z += a.y * b.z; c1w += a.y * b.w;
      c2x += a.z * b.x; c2y += a.z * b.y; c2z += a.z * b.z; c2w += a.z * b.w;
      c3x += a.w * b.x; c3y += a.w * b.y; c3z += a.w * b.z; c3w += a.w * b.w;
    }
    __syncthreads();
  }
  float* Co = Pout + (size_t)blockIdx.z * 262144;
  size_t o = (size_t)(bi + ty * 4) * Mrows + bj + tx * 4;
  *(float4*)&Co[o]             = make_float4(c0x, c0y, c0z, c0w);
  *(float4*)&Co[o + Mrows]     = make_float4(c1x, c1y, c1z, c1w);
  *(float4*)&Co[o + 2 * Mrows] = make_float4(c2x, c2y, c2z, c2w);
  *(float4*)&Co[o + 3 * Mrows] = make_float4(c3x, c3y, c3z, c3w);
}

// NS (c): Xn = 2*Xc - sum(P[4..7]). 256 blocks x 256 thr (float4 each).
__global__ void k_ns_c(const float* __restrict__ Xc, const float* __restrict__ P,
                       float* __restrict__ Xn) {
  const int i4 = blockIdx.x * 256 + threadIdx.x;
  float4 s = ((const float4*)(P + (size_t)4 * 262144))[i4];
#pragma unroll
  for (int q = 5; q < 8; q++) {
    const float4 v = ((const float4*)(P + (size_t)q * 262144))[i4];
    s.x += v.x; s.y += v.y; s.z += v.z; s.w += v.w;
  }
  const float4 xc = ((const float4*)Xc)[i4];
  ((float4*)Xn)[i4] = make_float4(2.f * xc.x - s.x, 2.f * xc.y - s.y,
                                  2.f * xc.z - s.z, 2.f * xc.w - s.w);
}

// ---------------------------------------------------------------------------
// fp64 512x512 GEMMs for R = X (I + E + E^2) => G R = I - E^3.
// ---------------------------------------------------------------------------
__global__ __launch_bounds__(256) void k_gemm_E(const float* __restrict__ G,
                                                const float* __restrict__ X,
                                                double* __restrict__ E) {
  __shared__ float Gs[32][33], Xs[32][33];
  const int tid = threadIdx.x;
  const int tx = tid & 15, ty = tid >> 4;
  const int bi = blockIdx.y * 32, bj = blockIdx.x * 32;
  const int r0 = ty * 2, c0 = tx * 2;
  double a00 = 0, a01 = 0, a10 = 0, a11 = 0;
  for (int k0 = 0; k0 < Mrows; k0 += 32) {
#pragma unroll
    for (int l = 0; l < 4; l++) {
      int e = tid + l * 256;
      int rr = e >> 5, cc = e & 31;
      Gs[rr][cc] = G[(size_t)(bi + rr) * Mrows + k0 + cc];
      Xs[rr][cc] = X[(size_t)(k0 + rr) * Mrows + bj + cc];
    }
    __syncthreads();
#pragma unroll
    for (int kk = 0; kk < 32; kk++) {
      double g0 = Gs[r0][kk], g1 = Gs[r0 + 1][kk];
      double x0 = Xs[kk][c0], x1 = Xs[kk][c0 + 1];
      a00 += g0 * x0; a01 += g0 * x1; a10 += g1 * x0; a11 += g1 * x1;
    }
    __syncthreads();
  }
  size_t o = (size_t)(bi + r0) * Mrows + bj + c0;
  E[o] = ((bi + r0) == (bj + c0) ? 1.0 : 0.0) - a00;
  E[o + 1] = ((bi + r0) == (bj + c0 + 1) ? 1.0 : 0.0) - a01;
  E[o + Mrows] = ((bi + r0 + 1) == (bj + c0) ? 1.0 : 0.0) - a10;
  E[o + Mrows + 1] = ((bi + r0 + 1) == (bj + c0 + 1) ? 1.0 : 0.0) - a11;
}

__global__ __launch_bounds__(256) void k_gemm_XE(const float* __restrict__ X,
                                                 const double* __restrict__ E,
                                                 double* __restrict__ U) {
  __shared__ float Xs[32][33];
  __shared__ double Es[32][33];
  const int tid = threadIdx.x;
  const int tx = tid & 15, ty = tid >> 4;
  const int bi = blockIdx.y * 32, bj = blockIdx.x * 32;
  const int r0 = ty * 2, c0 = tx * 2;
  double a00 = 0, a01 = 0, a10 = 0, a11 = 0;
  for (int k0 = 0; k0 < Mrows; k0 += 32) {
#pragma unroll
    for (int l = 0; l < 4; l++) {
      int e = tid + l * 256;
      int rr = e >> 5, cc = e & 31;
      Xs[rr][cc] = X[(size_t)(bi + rr) * Mrows + k0 + cc];
      Es[rr][cc] = E[(size_t)(k0 + rr) * Mrows + bj + cc];
    }
    __syncthreads();
#pragma unroll
    for (int kk = 0; kk < 32; kk++) {
      double x0 = Xs[r0][kk], x1 = Xs[r0 + 1][kk];
      double e0 = Es[kk][c0], e1 = Es[kk][c0 + 1];
      a00 += x0 * e0; a01 += x0 * e1; a10 += x1 * e0; a11 += x1 * e1;
    }
    __syncthreads();
  }
  size_t o = (size_t)(bi + r0) * Mrows + bj + c0;
  U[o] = a00; U[o + 1] = a01; U[o + Mrows] = a10; U[o + Mrows + 1] = a11;
}

// R = X + U + U*E  (fp64)  => R = X (I + E + E^2)
__global__ __launch_bounds__(256) void k_gemm_UER(const double* __restrict__ U,
                                                  const double* __restrict__ E,
                                                  const float* __restrict__ Xf,
                                                  double* __restrict__ R) {
  __shared__ double Us[32][33];
  __shared__ double Es[32][33];
  const int tid = threadIdx.x;
  const int tx = tid & 15, ty = tid >> 4;
  const int bi = blockIdx.y * 32, bj = blockIdx.x * 32;
  const int r0 = ty * 2, c0 = tx * 2;
  double a00 = 0, a01 = 0, a10 = 0, a11 = 0;
  for (int k0 = 0; k0 < Mrows; k0 += 32) {
#pragma unroll
    for (int l = 0; l < 4; l++) {
      int e = tid + l * 256;
      int rr = e >> 5, cc = e & 31;
      Us[rr][cc] = U[(size_t)(bi + rr) * Mrows + k0 + cc];
      Es[rr][cc] = E[(size_t)(k0 + rr) * Mrows + bj + cc];
    }
    __syncthreads();
#pragma unroll
    for (int kk = 0; kk < 32; kk++) {
      double u0 = Us[r0][kk], u1 = Us[r0 + 1][kk];
      double e0 = Es[kk][c0], e1 = Es[kk][c0 + 1];
      a00 += u0 * e0; a01 += u0 * e1; a10 += u1 * e0; a11 += u1 * e1;
    }
    __syncthreads();
  }
  size_t o = (size_t)(bi + r0) * Mrows + bj + c0;
  R[o]     = (double)Xf[o] + U[o] + a00;
  R[o + 1] = (double)Xf[o + 1] + U[o + 1] + a01;
  R[o + Mrows] = (double)Xf[o + Mrows] + U[o + Mrows] + a10;
  R[o + Mrows + 1] = (double)Xf[o + Mrows + 1] + U[o + Mrows + 1] + a11;
}

// y = R * rhs (fp64 matvec, 512 blocks x 64 thr). [proven R6]
__global__ __launch_bounds__(64) void k_solveR(const double* __restrict__ R,
                                               const float* __restrict__ rhs_f,
                                               const double* __restrict__ rhs_d,
                                               double* __restrict__ y,
                                               const int* __restrict__ flag, int chk) {
  if (chk && *flag) return;
  const int m = blockIdx.x, t = threadIdx.x;
  const double2* Rr = (const double2*)(R + (size_t)m * Mrows);
  double acc = 0.0;
#pragma unroll
  for (int i = 0; i < 4; i++) {
    int i2 = t + 64 * i;
    double2 a = Rr[i2];
    double x0, x1;
    if (rhs_f) { x0 = rhs_f[i2 * 2]; x1 = rhs_f[i2 * 2 + 1]; }
    else       { x0 = rhs_d[i2 * 2]; x1 = rhs_d[i2 * 2 + 1]; }
    acc += a.x * x0 + a.y * x1;
  }
  acc = wredD(acc);
  if (t == 0) y[m] = acc;
}

// t1d[m] = fp64 dot(A[m,:], v), 512 blocks x 256. [proven R6]
__global__ __launch_bounds__(256) void k_mv_A(const float* __restrict__ Mat,
                                              const float* __restrict__ v,
                                              double* __restrict__ t1d,
                                              const int* __restrict__ flag, int chk) {
  if (chk && *flag) return;
  const int m = blockIdx.x, tid = threadIdx.x;
  const float4* Mr = (const float4*)(Mat + (size_t)m * Ncols);
  const float4* v4 = (const float4*)v;
  double acc = 0.0;
#pragma unroll
  for (int i = 0; i < 4; i++) {
    float4 a = Mr[tid + 256 * i];
    float4 x = v4[tid + 256 * i];
    acc += (double)a.x * x.x + (double)a.y * x.y + (double)a.z * x.z + (double)a.w * x.w;
  }
  __shared__ double sb[4];
  acc = wredD(acc);
  const int lane = tid & 63, wid = tid >> 6;
  if (!lane) sb[wid] = acc;
  __syncthreads();
  if (!tid) t1d[m] = sb[0] + sb[1] + sb[2] + sb[3];
}

// ---------------------------------------------------------------------------
// Bp = B p with the PREVIOUS iteration's CG update fused in (R11).
// 1024 blocks x 256 thr, 4 rows/block. When upd=1: every block replicates the
// k_vup scalar reduce from dotbuf (bitwise-identical order), computes p_new
// into its own LDS; blocks 0..15 write disjoint slices of p_cur/r_cur/dv.
// Ping-pong p/r buffers: readers only touch *_prev, writers only *_cur.
// ---------------------------------------------------------------------------
__global__ __launch_bounds__(256) void k_mv_B4u(const float* __restrict__ B,
                                                const float* __restrict__ p_prev,
                                                float* __restrict__ p_cur,
                                                const float* __restrict__ r_prev,
                                                float* __restrict__ r_cur,
                                                const float* __restrict__ PBp,
                                                const double* __restrict__ dotbuf,
                                                float* __restrict__ dv,
                                                float* __restrict__ Bp,
                                                int* __restrict__ flag, int upd) {
  if (flag[0]) return;
  __shared__ float4 ps[1024];
  __shared__ double sdd[20];
  const int tid = threadIdx.x;
  const int wid = tid >> 6, lane = tid & 63;
  if (!upd) {
#pragma unroll
    for (int l = 0; l < 4; l++)
      ps[tid + 256 * l] = ((const float4*)p_cur)[tid + 256 * l];
  } else {
#pragma unroll
    for (int d = 0; d < 5; d++) {
      double v = dotbuf[d * 256 + tid];
      v = wredD(v);
      if (!lane) sdd[d * 4 + wid] = v;
    }
    __syncthreads();
    double tot[5];
#pragma unroll
    for (int d = 0; d < 5; d++)
      tot[d] = sdd[d * 4] + sdd[d * 4 + 1] + sdd[d * 4 + 2] + sdd[d * 4 + 3];
    const double pPBp = tot[0], pp = tot[1], rPBp = tot[2], PBp2 = tot[3], rr = tot[4];
    if (pPBp <= 1e-6 * pp) { if (tid == 0) flag[0] = 1; return; }
    const double alpha = rr / fmax(pPBp, 1e-300);
    double rn2 = rr - 2.0 * alpha * rPBp + alpha * alpha * PBp2;
    rn2 = fmax(rn2, 0.0);
    const double beta = rn2 / fmax(rr, 1e-300);
    const bool wb = (blockIdx.x < 16);
#pragma unroll
    for (int l = 0; l < 4; l++) {
      const int i4 = tid + 256 * l;
      const float4 pv = ((const float4*)p_prev)[i4];
      const float4 rv = ((const float4*)r_prev)[i4];
      const float4 qv = ((const float4*)PBp)[i4];
      const double rd0 = (double)rv.x - alpha * (double)qv.x;
      const double rd1 = (double)rv.y - alpha * (double)qv.y;
      const double rd2 = (double)rv.z - alpha * (double)qv.z;
      const double rd3 = (double)rv.w - alpha * (double)qv.w;
      const float4 pn = make_float4((float)(rd0 + beta * (double)pv.x),
                                    (float)(rd1 + beta * (double)pv.y),
                                    (float)(rd2 + beta * (double)pv.z),
                                    (float)(rd3 + beta * (double)pv.w));
      ps[i4] = pn;
      if (wb && (i4 >> 6) == (int)blockIdx.x) {
        ((float4*)p_cur)[i4] = pn;
        ((float4*)r_cur)[i4] =
            make_float4((float)rd0, (float)rd1, (float)rd2, (float)rd3);
        float4 dvv = ((float4*)dv)[i4];
        dvv.x = (float)((double)dvv.x + alpha * (double)pv.x);
        dvv.y = (float)((double)dvv.y + alpha * (double)pv.y);
        dvv.z = (float)((double)dvv.z + alpha * (double)pv.z);
        dvv.w = (float)((double)dvv.w + alpha * (double)pv.w);
        ((float4*)dv)[i4] = dvv;
      }
    }
    if (rn2 < 1e-16) {  // converged: updates written, skip this matvec
      if (tid == 0 && blockIdx.x == 0) flag[0] = 1;
      return;
    }
  }
  __syncthreads();
  const int row = blockIdx.x * 4 + wid;
  const float4* Br = (const float4*)(B + (size_t)row * Ncols);
  double acc = 0.0;
#pragma unroll
  for (int i = 0; i < 16; i++) {
    const float4 a = Br[lane + 64 * i];
    const float4 x = ps[lane + 64 * i];
    acc += (double)a.x * x.x + (double)a.y * x.y + (double)a.z * x.z + (double)a.w * x.w;
  }
  acc = wredD(acc);
  if (!lane) Bp[row] = (float)acc;
}

// Setup outputs + CG init. [proven R6]
__global__ __launch_bounds__(256) void k_setup_fin(const float* __restrict__ A,
                                                   const double* __restrict__ y0d,
                                                   const double* __restrict__ y1d,
                                                   const float* __restrict__ g,
                                                   float* __restrict__ out,
                                                   float* __restrict__ r,
                                                   float* __restrict__ p,
                                                   float* __restrict__ dv) {
  __shared__ double y0s[512], y1s[512];
  const int tid = threadIdx.x;
  y0s[tid] = y0d[tid]; y0s[tid + 256] = y0d[tid + 256];
  y1s[tid] = y1d[tid]; y1s[tid + 256] = y1d[tid + 256];
  __syncthreads();
  const int col = blockIdx.x * 256 + tid;
  double xa = 0.0, ra = 0.0;
  for (int m = 0; m < Mrows; m++) {
    double av = (double)A[(size_t)m * Ncols + col];
    xa += av * y0s[m];
    ra += av * y1s[m];
  }
  out[col] = (float)xa;
  float rv = (float)(ra - (double)g[col]);
  r[col] = rv; p[col] = rv; dv[col] = 0.f;
}

// ---------------------------------------------------------------------------
// PBp = Bp - A^T y ; fresh fp64 dots {p.PBp, p.p, r.PBp, PBp.PBp, r.r}
// -> dotbuf[d*256 + bid]. 256 blocks x 256 thr, 16 cols/block, m 16-split.
// ---------------------------------------------------------------------------
__global__ __launch_bounds__(256) void k_pcc3(const float* __restrict__ A,
                                              const double* __restrict__ yd,
                                              const float* __restrict__ Bp,
                                              const float* __restrict__ p,
                                              const float* __restrict__ r,
                                              float* __restrict__ PBp,
                                              double* __restrict__ dotbuf,
                                              const int* __restrict__ flag) {
  if (*flag) return;
  __shared__ double ysh[512];
  __shared__ double part[256];
  __shared__ double d5[80];
  const int tid = threadIdx.x;
  ysh[tid] = yd[tid]; ysh[tid + 256] = yd[tid + 256];
  __syncthreads();
  const int cl = tid & 15, ms = tid >> 4;
  const int col = blockIdx.x * 16 + cl;
  double acc = 0.0;
  for (int m = ms * 32; m < ms * 32 + 32; m++)
    acc += (double)A[(size_t)m * Ncols + col] * ysh[m];
  part[ms * 16 + cl] = acc;
  __syncthreads();
  if (tid < 16) {
    const int c = blockIdx.x * 16 + tid;
    double s = 0.0;
#pragma unroll
    for (int q = 0; q < 16; q++) s += part[q * 16 + tid];
    const double pb = (double)Bp[c] - s;
    PBp[c] = (float)pb;
    const double pi = (double)p[c];
    const double ri = (double)r[c];
    d5[0 * 16 + tid] = pi * pb;
    d5[1 * 16 + tid] = pi * pi;
    d5[2 * 16 + tid] = ri * pb;
    d5[3 * 16 + tid] = pb * pb;
    d5[4 * 16 + tid] = ri * ri;
  }
  __syncthreads();
  if (tid < 5) {
    double s = 0.0;
#pragma unroll
    for (int c = 0; c < 16; c++) s += d5[tid * 16 + c];
    dotbuf[tid * 256 + blockIdx.x] = s;
  }
}

// Final dv update for the LAST CG iteration (16 blocks x 256).
__global__ __launch_bounds__(256) void k_vup_fin(float* __restrict__ dv,
                                                 const float* __restrict__ p_last,
                                                 const double* __restrict__ dotbuf,
                                                 const int* __restrict__ flag) {
  if (*flag) return;
  __shared__ double sdd[20];
  const int tid = threadIdx.x;
  const int wid = tid >> 6, lane = tid & 63;
#pragma unroll
  for (int d = 0; d < 5; d++) {
    double v = dotbuf[d * 256 + tid];
    v = wredD(v);
    if (!lane) sdd[d * 4 + wid] = v;
  }
  __syncthreads();
  double tot[5];
#pragma unroll
  for (int d = 0; d < 5; d++)
    tot[d] = sdd[d * 4] + sdd[d * 4 + 1] + sdd[d * 4 + 2] + sdd[d * 4 + 3];
  const double pPBp = tot[0], pp = tot[1], rr = tot[4];
  if (pPBp <= 1e-6 * pp) return;   // bad curvature: no update (matches k_vup)
  const double alpha = rr / fmax(pPBp, 1e-300);
  const int idx = blockIdx.x * 256 + tid;
  dv[idx] = (float)((double)dv[idx] + alpha * (double)p_last[idx]);
}

// out[4096+col] = dv[col] - (A^T yd)[col]. [proven R6]
__global__ __launch_bounds__(256) void k_final_d(const float* __restrict__ A,
                                                 const double* __restrict__ yd,
                                                 const float* __restrict__ dv,
                                                 float* __restrict__ out) {
  __shared__ double ysm[512];
  const int tid = threadIdx.x;
  ysm[tid] = yd[tid]; ysm[tid + 256] = yd[tid + 256];
  __syncthreads();
  const int col = blockIdx.x * 256 + tid;
  double acc = 0.0;
  for (int m = 0; m < Mrows; m++) acc += (double)A[(size_t)m * Ncols + col] * ysm[m];
  out[Ncols + col] = (float)((double)dv[col] - acc);
}

// ---------------------------------------------------------------------------
extern "C" void kernel_launch(void* const* d_in, const int* in_sizes, int n_in,
                              void* d_out, int out_size, void* d_ws, size_t ws_size,
                              hipStream_t stream) {
  const float* A = (const float*)d_in[0];   // 512 x 4096
  const float* b = (const float*)d_in[1];   // 512
  const float* B = (const float*)d_in[2];   // 4096 x 4096
  const float* g = (const float*)d_in[3];   // 4096
  float* out = (float*)d_out;               // x[4096] then d[4096]
  float* ws = (float*)d_ws;

  // NOTE aliasing is ordering-safe: aat writes P[0..31] (ws+1048576 ..
  // ws+9437184 floats, ~37.7MB) FIRST; redG consumes; all later buffers in
  // that range (Ed/Ud/Rd, CG vectors, dotbuf, flag, p2/r2) are written after.
  float*  G   = ws;                         // 262144 floats
  float*  Xa  = ws + 262144;
  float*  Xb  = ws + 524288;
  float*  P   = ws + 1048576;               // 32 x 262144 (AAT) / 8 (NS)
  double* Ed  = (double*)(ws + 1048576);    // aliases P (used after NS only)
  double* Ud  = (double*)(ws + 1572864);    // aliases P
  double* Rd  = (double*)(ws + 3145728);    // 512x512 fp64
  float*  Bp  = ws + 3670016;               // 4096 each
  float*  PBp = ws + 3674112;
  float*  r   = ws + 3678208;
  float*  p   = ws + 3682304;
  float*  dv  = ws + 3686400;
  double* t1d = (double*)(ws + 3690496);    // 512 doubles
  double* y0d = (double*)(ws + 3691520);
  double* y1d = (double*)(ws + 3692544);
  double* dotbuf = (double*)(ws + 3693568); // 5 x 256 doubles
  int*    flag   = (int*)(ws + 3696132);
  float*  p2  = ws + 3696144;               // ping-pong partners (R11)
  float*  r2  = ws + 3700240;

  // --- G = A A^T (32 K-slices, 128^2 tiles, 8x8/thread) ; row-reduce ---
  k_aat_part<<<dim3(4, 4, 32), 256, 0, stream>>>(A, P);
  k_redG<<<Mrows, 64, 0, stream>>>(P, G);

  // --- X0 = c0 I + c1 G + c2 G^2 (degree-2 Chebyshev, R14(b)) ---
  k_ns_a<<<dim3(8, 8, 4), 256, 0, stream>>>(G, G, P);          // P[0..3] = G*G
  k_init2s<<<256, 256, 0, stream>>>(Xa, G, P, flag);

  // --- Newton-Schulz: X' = 2X - X(GX), 2 iters, 3 kernels each ---
  float* Xcur = Xa;
  float* Xnxt = Xb;
  for (int it = 0; it < 2; it++) {
    k_ns_a<<<dim3(8, 8, 4), 256, 0, stream>>>(G, Xcur, P);      // P[0..3] = G*X
    k_ns_b<<<dim3(8, 8, 4), 256, 0, stream>>>(Xcur, P, P + 4 * 262144);  // P[4..7] = X*T
    k_ns_c<<<256, 256, 0, stream>>>(Xcur, P, Xnxt);             // Xn = 2X - sum
    float* tmp = Xcur; Xcur = Xnxt; Xnxt = tmp;
  }

  // --- R = X (I+E+E^2), E = I - G X : G*R = I - E^3 (fp64) ---
  k_gemm_E<<<dim3(16, 16), 256, 0, stream>>>(G, Xcur, Ed);
  k_gemm_XE<<<dim3(16, 16), 256, 0, stream>>>(Xcur, Ed, Ud);
  k_gemm_UER<<<dim3(16, 16), 256, 0, stream>>>(Ud, Ed, Xcur, Rd);

  // --- x = A^T R b ; r0 = p = A^T R (A g) - g ---
  k_mv_A<<<Mrows, 256, 0, stream>>>(A, g, t1d, flag, 0);
  k_solveR<<<Mrows, 64, 0, stream>>>(Rd, b, (const double*)0, y0d, flag, 0);
  k_solveR<<<Mrows, 64, 0, stream>>>(Rd, (const float*)0, t1d, y1d, flag, 0);
  k_setup_fin<<<16, 256, 0, stream>>>(A, y0d, y1d, g, out, r, p, dv);

  // --- projected CG, CG_ITERS iterations, 4 launches/iter ---
  float* pb[2] = {p, p2};
  float* rb[2] = {r, r2};
  for (int it = 0; it < CG_ITERS; it++) {
    const int cur = it & 1, prv = cur ^ 1;
    if (it == 0)
      k_mv_B4u<<<1024, 256, 0, stream>>>(B, pb[0], pb[0], rb[0], rb[0], PBp,
                                         dotbuf, dv, Bp, flag, 0);
    else
      k_mv_B4u<<<1024, 256, 0, stream>>>(B, pb[prv], pb[cur], rb[prv], rb[cur],
                                         PBp, dotbuf, dv, Bp, flag, 1);
    k_mv_A<<<Mrows, 256, 0, stream>>>(A, Bp, t1d, flag, 1);
    k_solveR<<<Mrows, 64, 0, stream>>>(Rd, (const float*)0, t1d, y1d, flag, 1);
    k_pcc3<<<256, 256, 0, stream>>>(A, y1d, Bp, pb[cur], rb[cur], PBp, dotbuf, flag);
  }
  k_vup_fin<<<16, 256, 0, stream>>>(dv, pb[(CG_ITERS - 1) & 1], dotbuf, flag);

  // --- d_out = P(dv): strip row-space contamination ---
  k_mv_A<<<Mrows, 256, 0, stream>>>(A, dv, t1d, flag, 0);
  k_solveR<<<Mrows, 64, 0, stream>>>(Rd, (const float*)0, t1d, y1d, flag, 0);
  k_final_d<<<16, 256, 0, stream>>>(A, y1d, dv, out);
}

// Round 11
// 455.958 us; speedup vs baseline: 1.1022x; 1.0219x over previous
//
#include <hip/hip_runtime.h>
#include <hip/hip_bf16.h>

// ProjectedCGCraig on MI355X (gfx950).
//   x = A^T G^{-1} b,  G = A A^T (512x512)
//   d = projected CG with P v = v - A^T G^{-1} A v
// LESSON (R3): per-iteration projection must be refinement-exact (<=1e-9).
// LESSON (R5): CG scalars MEASURED fresh from stored fp32 vectors each iter.
// LESSON (R7): grid.sync() ~28us; launches (~2.2us) are the cheap grid sync.
// LESSON (R9->R10): LAST-BLOCK-ticket fold REGRESSED ~+100us. Launch
//   boundary IS the cheap handoff. (Replicated-reduce + disjoint-slice
//   writes + ping-pong buffers is the SAFE fold pattern - proven R11.)
// LESSON (R14->R15): LDS row pad must keep rows 16B-ALIGNED (pad 130 ->
//   ds_read_b64 fallback, 2x LDS instr). Pad 132 restores b128.
// LESSON (R8-R10 submit): reply must contain EXACTLY ONE fence pair and no
//   backtick runs anywhere else (prose or comments) - the block parser
//   re-segments on any stray fence.
// R16 (this round):
//   (a) aat SINGLE-BUFFER (33.8KB): decides H1-vs-H2 for the remaining
//       46-vs-23us gap. H1 (2x67.6KB blocks failed to co-reside -> two
//       1-block/CU passes) -> ~27us. H2 (b128 with 4x lane-broadcast fetches
//       only 256B unique -> ~24cyc/read; LDS-pipe-work-bound) -> stays ~45
//       and aat is AT its floor (pre-committed: stop optimizing it).
//   (b) head: merge the two independent solveRs into one 1024-block launch.
//   (c) tail: fold k_vup_fin into k_mv_A (k_mv_A_up): replicated dotbuf
//       reduce, t1 = A*(dv + alpha*p) in fp64, blocks 0..15 write dv2
//       (ping-pong vs dv -> race-free); k_final_d consumes dv2.
// R11: CG fused update (k_mv_B4u). R12/R13: Chebyshev init on [0.35,2.0],
// CG=5, cubic refine. R14(b): degree-2 init X0 = c0 I + c1 G + c2 G^2, NS=2.
// M=512, N=4096 fixed.

#define Mrows 512
#define Ncols 4096
#define CG_ITERS 5
#define AAT_PAD 132

__device__ __forceinline__ float wredF(float v) {
#pragma unroll
  for (int off = 32; off; off >>= 1) v += __shfl_down(v, off, 64);
  return v;
}
__device__ __forceinline__ double wredD(double v) {
#pragma unroll
  for (int off = 32; off; off >>= 1) v += __shfl_down(v, off, 64);
  return v;
}

// ---------------------------------------------------------------------------
// Partial AAT: slice bz = A[bi..+128][Kb..+128] * A[bj..+128][..]^T.
// grid (4,4,32), 256 thr, 8x8 micro-tile. R16(a): SINGLE-buffer LDS 33.8KB
// (2 barriers/step, reg prefetch) -> up to 4 blocks/CU. FMA order unchanged
// vs R15 -> G bitwise identical.
// ---------------------------------------------------------------------------
__global__ __launch_bounds__(256) void k_aat_part(const float* __restrict__ A,
                                                  float* __restrict__ P) {
  __shared__ __align__(16) float At[32][AAT_PAD];
  __shared__ __align__(16) float Bt[32][AAT_PAD];
  const int tid = threadIdx.x;
  const int tx = tid & 15, ty = tid >> 4;
  const int bj = blockIdx.x * 128, bi = blockIdx.y * 128;
  const int Kb = blockIdx.z * 128;
  const int ar = tid >> 3, ak = tid & 7;
  const int ak4 = ak * 4, ty4 = ty * 4, tx4 = tx * 4;
  const float* pa0 = &A[(size_t)(bi + ar) * Ncols + Kb + ak4];
  const float* pa1 = pa0 + (size_t)32 * Ncols;
  const float* pa2 = pa0 + (size_t)64 * Ncols;
  const float* pa3 = pa0 + (size_t)96 * Ncols;
  const float* pb0 = &A[(size_t)(bj + ar) * Ncols + Kb + ak4];
  const float* pb1 = pb0 + (size_t)32 * Ncols;
  const float* pb2 = pb0 + (size_t)64 * Ncols;
  const float* pb3 = pb0 + (size_t)96 * Ncols;
  float4 ra0 = *(const float4*)pa0, ra1 = *(const float4*)pa1;
  float4 ra2 = *(const float4*)pa2, ra3 = *(const float4*)pa3;
  float4 rb0 = *(const float4*)pb0, rb1 = *(const float4*)pb1;
  float4 rb2 = *(const float4*)pb2, rb3 = *(const float4*)pb3;
  float4 c[8][2];
#pragma unroll
  for (int i = 0; i < 8; i++) {
    c[i][0] = make_float4(0.f, 0.f, 0.f, 0.f);
    c[i][1] = make_float4(0.f, 0.f, 0.f, 0.f);
  }
  for (int s = 0; s < 4; ++s) {
    if (s) __syncthreads();   // previous step's reads complete before overwrite
    At[ak4 + 0][ar] = ra0.x; At[ak4 + 1][ar] = ra0.y;
    At[ak4 + 2][ar] = ra0.z; At[ak4 + 3][ar] = ra0.w;
    At[ak4 + 0][ar + 32] = ra1.x; At[ak4 + 1][ar + 32] = ra1.y;
    At[ak4 + 2][ar + 32] = ra1.z; At[ak4 + 3][ar + 32] = ra1.w;
    At[ak4 + 0][ar + 64] = ra2.x; At[ak4 + 1][ar + 64] = ra2.y;
    At[ak4 + 2][ar + 64] = ra2.z; At[ak4 + 3][ar + 64] = ra2.w;
    At[ak4 + 0][ar + 96] = ra3.x; At[ak4 + 1][ar + 96] = ra3.y;
    At[ak4 + 2][ar + 96] = ra3.z; At[ak4 + 3][ar + 96] = ra3.w;
    Bt[ak4 + 0][ar] = rb0.x; Bt[ak4 + 1][ar] = rb0.y;
    Bt[ak4 + 2][ar] = rb0.z; Bt[ak4 + 3][ar] = rb0.w;
    Bt[ak4 + 0][ar + 32] = rb1.x; Bt[ak4 + 1][ar + 32] = rb1.y;
    Bt[ak4 + 2][ar + 32] = rb1.z; Bt[ak4 + 3][ar + 32] = rb1.w;
    Bt[ak4 + 0][ar + 64] = rb2.x; Bt[ak4 + 1][ar + 64] = rb2.y;
    Bt[ak4 + 2][ar + 64] = rb2.z; Bt[ak4 + 3][ar + 64] = rb2.w;
    Bt[ak4 + 0][ar + 96] = rb3.x; Bt[ak4 + 1][ar + 96] = rb3.y;
    Bt[ak4 + 2][ar + 96] = rb3.z; Bt[ak4 + 3][ar + 96] = rb3.w;
    __syncthreads();
    if (s < 3) {
      const int off = (s + 1) * 32;
      ra0 = *(const float4*)(pa0 + off); ra1 = *(const float4*)(pa1 + off);
      ra2 = *(const float4*)(pa2 + off); ra3 = *(const float4*)(pa3 + off);
      rb0 = *(const float4*)(pb0 + off); rb1 = *(const float4*)(pb1 + off);
      rb2 = *(const float4*)(pb2 + off); rb3 = *(const float4*)(pb3 + off);
    }
#pragma unroll
    for (int kk = 0; kk < 32; kk++) {
      const float4 a0 = *(const float4*)&At[kk][ty4];
      const float4 a1 = *(const float4*)&At[kk][64 + ty4];
      const float4 b0 = *(const float4*)&Bt[kk][tx4];
      const float4 b1 = *(const float4*)&Bt[kk][64 + tx4];
      const float av[8] = {a0.x, a0.y, a0.z, a0.w, a1.x, a1.y, a1.z, a1.w};
#pragma unroll
      for (int i = 0; i < 8; i++) {
        c[i][0].x += av[i] * b0.x; c[i][0].y += av[i] * b0.y;
        c[i][0].z += av[i] * b0.z; c[i][0].w += av[i] * b0.w;
        c[i][1].x += av[i] * b1.x; c[i][1].y += av[i] * b1.y;
        c[i][1].z += av[i] * b1.z; c[i][1].w += av[i] * b1.w;
      }
    }
  }
  float* Co = P + (size_t)blockIdx.z * 262144;
#pragma unroll
  for (int i = 0; i < 8; i++) {
    const int row = bi + ((i < 4) ? (ty4 + i) : (64 + ty4 + (i - 4)));
    const size_t o = (size_t)row * Mrows + bj;
    *(float4*)&Co[o + tx4]      = c[i][0];
    *(float4*)&Co[o + 64 + tx4] = c[i][1];
  }
}

// ---------------------------------------------------------------------------
// G row = sum of 32 AAT partials. 512 blocks x 64 thr.
// ---------------------------------------------------------------------------
__global__ __launch_bounds__(64) void k_redG(const float* __restrict__ P,
                                             float* __restrict__ G) {
  const int row = blockIdx.x, lane = threadIdx.x;
#pragma unroll
  for (int j = 0; j < 2; j++) {
    const int i4 = row * 128 + lane + 64 * j;
    float4 s = ((const float4*)P)[i4];
#pragma unroll
    for (int q = 1; q < 32; q++) {
      const float4 v = ((const float4*)(P + (size_t)q * 262144))[i4];
      s.x += v.x; s.y += v.y; s.z += v.z; s.w += v.w;
    }
    ((float4*)G)[i4] = s;
  }
}

// ---------------------------------------------------------------------------
// X0 = c0 I + c1 G + c2 G^2 : degree-2 Chebyshev p(lambda) ~ 1/lambda on
// [0.35, 2.0]. E0 = 1/T3(1.4242) = 0.13730. G^2 partials from k_ns_a(G,G,P).
// ---------------------------------------------------------------------------
__global__ void k_init2s(float* __restrict__ X, const float* __restrict__ G,
                         const float* __restrict__ P, int* __restrict__ flag) {
  const float c0 = 3.5517450f;
  const float c1 = -3.4476528f;
  const float c2 = 0.9780600f;
  const int i4 = blockIdx.x * 256 + threadIdx.x;  // 0..65535
  float4 s = ((const float4*)P)[i4];
#pragma unroll
  for (int q = 1; q < 4; q++) {
    const float4 v = ((const float4*)(P + (size_t)q * 262144))[i4];
    s.x += v.x; s.y += v.y; s.z += v.z; s.w += v.w;
  }
  const float4 g4 = ((const float4*)G)[i4];
  const int e0 = i4 * 4;
  const int row = e0 >> 9, cb = e0 & 511;
  float4 xv;
  xv.x = c2 * s.x + c1 * g4.x + ((cb + 0) == row ? c0 : 0.f);
  xv.y = c2 * s.y + c1 * g4.y + ((cb + 1) == row ? c0 : 0.f);
  xv.z = c2 * s.z + c1 * g4.z + ((cb + 2) == row ? c0 : 0.f);
  xv.w = c2 * s.w + c1 * g4.w + ((cb + 3) == row ? c0 : 0.f);
  ((float4*)X)[i4] = xv;
  if (i4 == 0) { flag[0] = 0; flag[1] = 0; }
}

// ---------------------------------------------------------------------------
// NS (a): P[0..3] = G * Xc partials. grid (8,8,4), K-slice 128, 256 thr.
// (Also reused as the G^2 partial GEMM with Xc = G.)
// ---------------------------------------------------------------------------
__global__ __launch_bounds__(256) void k_ns_a(const float* __restrict__ G,
                                              const float* __restrict__ Xc,
                                              float* __restrict__ P) {
  __shared__ float At[2][32][68];
  __shared__ float Bt[2][32][68];
  const int tid = threadIdx.x;
  const int tx = tid & 15, ty = tid >> 4;
  const int bj = blockIdx.x * 64, bi = blockIdx.y * 64;
  const int Kb = blockIdx.z * 128;
  const int ar = tid >> 3, ak = tid & 7;
  const int br = tid >> 4, bc = tid & 15;
  const int ak4 = ak * 4, ty4 = ty * 4, tx4 = tx * 4, bc4 = bc * 4;
  const float* pa0 = &G[(size_t)(bi + ar) * Mrows + Kb + ak4];
  const float* pa1 = pa0 + (size_t)32 * Mrows;
  const float* pb0 = &Xc[(size_t)(Kb + br) * Mrows + bj + bc4];
  const float* pb1 = pb0 + (size_t)16 * Mrows;
  float4 ra0 = *(const float4*)pa0, ra1 = *(const float4*)pa1;
  float4 rb0 = *(const float4*)pb0, rb1 = *(const float4*)pb1;
  float c0x = 0.f, c0y = 0.f, c0z = 0.f, c0w = 0.f;
  float c1x = 0.f, c1y = 0.f, c1z = 0.f, c1w = 0.f;
  float c2x = 0.f, c2y = 0.f, c2z = 0.f, c2w = 0.f;
  float c3x = 0.f, c3y = 0.f, c3z = 0.f, c3w = 0.f;
  for (int s = 0; s < 4; ++s) {
    float (*Atc)[68] = At[s & 1];
    float (*Btc)[68] = Bt[s & 1];
    Atc[ak4 + 0][ar] = ra0.x; Atc[ak4 + 1][ar] = ra0.y;
    Atc[ak4 + 2][ar] = ra0.z; Atc[ak4 + 3][ar] = ra0.w;
    Atc[ak4 + 0][ar + 32] = ra1.x; Atc[ak4 + 1][ar + 32] = ra1.y;
    Atc[ak4 + 2][ar + 32] = ra1.z; Atc[ak4 + 3][ar + 32] = ra1.w;
    *(float4*)&Btc[br][bc4]      = rb0;
    *(float4*)&Btc[br + 16][bc4] = rb1;
    __syncthreads();
    if (s < 3) {
      const int offA = (s + 1) * 32;
      const size_t offB = (size_t)(s + 1) * 32 * Mrows;
      ra0 = *(const float4*)(pa0 + offA); ra1 = *(const float4*)(pa1 + offA);
      rb0 = *(const float4*)(pb0 + offB); rb1 = *(const float4*)(pb1 + offB);
    }
#pragma unroll
    for (int kk = 0; kk < 32; kk++) {
      float4 a = *(float4*)&Atc[kk][ty4];
      float4 b = *(float4*)&Btc[kk][tx4];
      c0x += a.x * b.x; c0y += a.x * b.y; c0z += a.x * b.z; c0w += a.x * b.w;
      c1x += a.y * b.x; c1y += a.y * b.y; c1z += a.y * b.z; c1w += a.y * b.w;
      c2x += a.z * b.x; c2y += a.z * b.y; c2z += a.z * b.z; c2w += a.z * b.w;
      c3x += a.w * b.x; c3y += a.w * b.y; c3z += a.w * b.z; c3w += a.w * b.w;
    }
  }
  float* Co = P + (size_t)blockIdx.z * 262144;
  size_t o = (size_t)(bi + ty4) * Mrows + bj + tx4;
  *(float4*)&Co[o]             = make_float4(c0x, c0y, c0z, c0w);
  *(float4*)&Co[o + Mrows]     = make_float4(c1x, c1y, c1z, c1w);
  *(float4*)&Co[o + 2 * Mrows] = make_float4(c2x, c2y, c2z, c2w);
  *(float4*)&Co[o + 3 * Mrows] = make_float4(c3x, c3y, c3z, c3w);
}

// ---------------------------------------------------------------------------
// NS (b): P[4..7] = Xc * T partials, T = sum(P[0..3]) folded into B-staging.
// grid (8,8,4). [fold logic proven in R7 coop phase (b)]
// ---------------------------------------------------------------------------
__global__ __launch_bounds__(256) void k_ns_b(const float* __restrict__ Xc,
                                              const float* __restrict__ P,
                                              float* __restrict__ Pout) {
  __shared__ float At[32][68];
  __shared__ float Bt[32][68];
  const int tid = threadIdx.x;
  const int tx = tid & 15, ty = tid >> 4;
  const int bj = blockIdx.x * 64, bi = blockIdx.y * 64;
  const int Kb = blockIdx.z * 128;
  float c0x = 0.f, c0y = 0.f, c0z = 0.f, c0w = 0.f;
  float c1x = 0.f, c1y = 0.f, c1z = 0.f, c1w = 0.f;
  float c2x = 0.f, c2y = 0.f, c2z = 0.f, c2w = 0.f;
  float c3x = 0.f, c3y = 0.f, c3z = 0.f, c3w = 0.f;
  for (int k0 = 0; k0 < 128; k0 += 32) {
#pragma unroll
    for (int l = 0; l < 2; l++) {
      int f = tid + l * 256;
      int ar = f >> 3, ak = f & 7;
      const float4 av = *(const float4*)&Xc[(size_t)(bi + ar) * Mrows + Kb + k0 + ak * 4];
      At[ak * 4 + 0][ar] = av.x; At[ak * 4 + 1][ar] = av.y;
      At[ak * 4 + 2][ar] = av.z; At[ak * 4 + 3][ar] = av.w;
      int br = f >> 4, bc = f & 15;
      const size_t bo = (size_t)(Kb + k0 + br) * Mrows + bj + bc * 4;
      float4 bs = *(const float4*)&P[bo];
#pragma unroll
      for (int q = 1; q < 4; q++) {
        const float4 v = *(const float4*)&P[bo + (size_t)q * 262144];
        bs.x += v.x; bs.y += v.y; bs.z += v.z; bs.w += v.w;
      }
      *(float4*)&Bt[br][bc * 4] = bs;
    }
    __syncthreads();
#pragma unroll
    for (int kk = 0; kk < 32; kk++) {
      float4 a = *(float4*)&At[kk][ty * 4];
      float4 b = *(float4*)&Bt[kk][tx * 4];
      c0x += a.x * b.x; c0y += a.x * b.y; c0z += a.x * b.z; c0w += a.x * b.w;
      c1x += a.y * b.x; c1y += a.y * b.y; c1z += a.y * b.z; c1w += a.y * b.w;
      c2x += a.z * b.x; c2y += a.z * b.y; c2z += a.z * b.z; c2w += a.z * b.w;
      c3x += a.w * b.x; c3y += a.w * b.y; c3z += a.w * b.z; c3w += a.w * b.w;
    }
    __syncthreads();
  }
  float* Co = Pout + (size_t)blockIdx.z * 262144;
  size_t o = (size_t)(bi + ty * 4) * Mrows + bj + tx * 4;
  *(float4*)&Co[o]             = make_float4(c0x, c0y, c0z, c0w);
  *(float4*)&Co[o + Mrows]     = make_float4(c1x, c1y, c1z, c1w);
  *(float4*)&Co[o + 2 * Mrows] = make_float4(c2x, c2y, c2z, c2w);
  *(float4*)&Co[o + 3 * Mrows] = make_float4(c3x, c3y, c3z, c3w);
}

// NS (c): Xn = 2*Xc - sum(P[4..7]). 256 blocks x 256 thr (float4 each).
__global__ void k_ns_c(const float* __restrict__ Xc, const float* __restrict__ P,
                       float* __restrict__ Xn) {
  const int i4 = blockIdx.x * 256 + threadIdx.x;
  float4 s = ((const float4*)(P + (size_t)4 * 262144))[i4];
#pragma unroll
  for (int q = 5; q < 8; q++) {
    const float4 v = ((const float4*)(P + (size_t)q * 262144))[i4];
    s.x += v.x; s.y += v.y; s.z += v.z; s.w += v.w;
  }
  const float4 xc = ((const float4*)Xc)[i4];
  ((float4*)Xn)[i4] = make_float4(2.f * xc.x - s.x, 2.f * xc.y - s.y,
                                  2.f * xc.z - s.z, 2.f * xc.w - s.w);
}

// ---------------------------------------------------------------------------
// fp64 512x512 GEMMs for R = X (I + E + E^2) => G R = I - E^3.
// ---------------------------------------------------------------------------
__global__ __launch_bounds__(256) void k_gemm_E(const float* __restrict__ G,
                                                const float* __restrict__ X,
                                                double* __restrict__ E) {
  __shared__ float Gs[32][33], Xs[32][33];
  const int tid = threadIdx.x;
  const int tx = tid & 15, ty = tid >> 4;
  const int bi = blockIdx.y * 32, bj = blockIdx.x * 32;
  const int r0 = ty * 2, c0 = tx * 2;
  double a00 = 0, a01 = 0, a10 = 0, a11 = 0;
  for (int k0 = 0; k0 < Mrows; k0 += 32) {
#pragma unroll
    for (int l = 0; l < 4; l++) {
      int e = tid + l * 256;
      int rr = e >> 5, cc = e & 31;
      Gs[rr][cc] = G[(size_t)(bi + rr) * Mrows + k0 + cc];
      Xs[rr][cc] = X[(size_t)(k0 + rr) * Mrows + bj + cc];
    }
    __syncthreads();
#pragma unroll
    for (int kk = 0; kk < 32; kk++) {
      double g0 = Gs[r0][kk], g1 = Gs[r0 + 1][kk];
      double x0 = Xs[kk][c0], x1 = Xs[kk][c0 + 1];
      a00 += g0 * x0; a01 += g0 * x1; a10 += g1 * x0; a11 += g1 * x1;
    }
    __syncthreads();
  }
  size_t o = (size_t)(bi + r0) * Mrows + bj + c0;
  E[o] = ((bi + r0) == (bj + c0) ? 1.0 : 0.0) - a00;
  E[o + 1] = ((bi + r0) == (bj + c0 + 1) ? 1.0 : 0.0) - a01;
  E[o + Mrows] = ((bi + r0 + 1) == (bj + c0) ? 1.0 : 0.0) - a10;
  E[o + Mrows + 1] = ((bi + r0 + 1) == (bj + c0 + 1) ? 1.0 : 0.0) - a11;
}

__global__ __launch_bounds__(256) void k_gemm_XE(const float* __restrict__ X,
                                                 const double* __restrict__ E,
                                                 double* __restrict__ U) {
  __shared__ float Xs[32][33];
  __shared__ double Es[32][33];
  const int tid = threadIdx.x;
  const int tx = tid & 15, ty = tid >> 4;
  const int bi = blockIdx.y * 32, bj = blockIdx.x * 32;
  const int r0 = ty * 2, c0 = tx * 2;
  double a00 = 0, a01 = 0, a10 = 0, a11 = 0;
  for (int k0 = 0; k0 < Mrows; k0 += 32) {
#pragma unroll
    for (int l = 0; l < 4; l++) {
      int e = tid + l * 256;
      int rr = e >> 5, cc = e & 31;
      Xs[rr][cc] = X[(size_t)(bi + rr) * Mrows + k0 + cc];
      Es[rr][cc] = E[(size_t)(k0 + rr) * Mrows + bj + cc];
    }
    __syncthreads();
#pragma unroll
    for (int kk = 0; kk < 32; kk++) {
      double x0 = Xs[r0][kk], x1 = Xs[r0 + 1][kk];
      double e0 = Es[kk][c0], e1 = Es[kk][c0 + 1];
      a00 += x0 * e0; a01 += x0 * e1; a10 += x1 * e0; a11 += x1 * e1;
    }
    __syncthreads();
  }
  size_t o = (size_t)(bi + r0) * Mrows + bj + c0;
  U[o] = a00; U[o + 1] = a01; U[o + Mrows] = a10; U[o + Mrows + 1] = a11;
}

// R = X + U + U*E  (fp64)  => R = X (I + E + E^2)
__global__ __launch_bounds__(256) void k_gemm_UER(const double* __restrict__ U,
                                                  const double* __restrict__ E,
                                                  const float* __restrict__ Xf,
                                                  double* __restrict__ R) {
  __shared__ double Us[32][33];
  __shared__ double Es[32][33];
  const int tid = threadIdx.x;
  const int tx = tid & 15, ty = tid >> 4;
  const int bi = blockIdx.y * 32, bj = blockIdx.x * 32;
  const int r0 = ty * 2, c0 = tx * 2;
  double a00 = 0, a01 = 0, a10 = 0, a11 = 0;
  for (int k0 = 0; k0 < Mrows; k0 += 32) {
#pragma unroll
    for (int l = 0; l < 4; l++) {
      int e = tid + l * 256;
      int rr = e >> 5, cc = e & 31;
      Us[rr][cc] = U[(size_t)(bi + rr) * Mrows + k0 + cc];
      Es[rr][cc] = E[(size_t)(k0 + rr) * Mrows + bj + cc];
    }
    __syncthreads();
#pragma unroll
    for (int kk = 0; kk < 32; kk++) {
      double u0 = Us[r0][kk], u1 = Us[r0 + 1][kk];
      double e0 = Es[kk][c0], e1 = Es[kk][c0 + 1];
      a00 += u0 * e0; a01 += u0 * e1; a10 += u1 * e0; a11 += u1 * e1;
    }
    __syncthreads();
  }
  size_t o = (size_t)(bi + r0) * Mrows + bj + c0;
  R[o]     = (double)Xf[o] + U[o] + a00;
  R[o + 1] = (double)Xf[o + 1] + U[o + 1] + a01;
  R[o + Mrows] = (double)Xf[o + Mrows] + U[o + Mrows] + a10;
  R[o + Mrows + 1] = (double)Xf[o + Mrows + 1] + U[o + Mrows + 1] + a11;
}

// y = R * rhs (fp64 matvec, 512 blocks x 64 thr). [proven R6]
__global__ __launch_bounds__(64) void k_solveR(const double* __restrict__ R,
                                               const float* __restrict__ rhs_f,
                                               const double* __restrict__ rhs_d,
                                               double* __restrict__ y,
                                               const int* __restrict__ flag, int chk) {
  if (chk && *flag) return;
  const int m = blockIdx.x, t = threadIdx.x;
  const double2* Rr = (const double2*)(R + (size_t)m * Mrows);
  double acc = 0.0;
#pragma unroll
  for (int i = 0; i < 4; i++) {
    int i2 = t + 64 * i;
    double2 a = Rr[i2];
    double x0, x1;
    if (rhs_f) { x0 = rhs_f[i2 * 2]; x1 = rhs_f[i2 * 2 + 1]; }
    else       { x0 = rhs_d[i2 * 2]; x1 = rhs_d[i2 * 2 + 1]; }
    acc += a.x * x0 + a.y * x1;
  }
  acc = wredD(acc);
  if (t == 0) y[m] = acc;
}

// R16(b): head merge - 1024 blocks: [0,512) y0 = R b ; [512,1024) y1 = R t1d.
__global__ __launch_bounds__(64) void k_solveR2(const double* __restrict__ R,
                                                const float* __restrict__ bv,
                                                const double* __restrict__ t1d,
                                                double* __restrict__ y0,
                                                double* __restrict__ y1) {
  const int m = blockIdx.x & 511;
  const int sec = blockIdx.x >> 9;
  const int t = threadIdx.x;
  const double2* Rr = (const double2*)(R + (size_t)m * Mrows);
  double acc = 0.0;
#pragma unroll
  for (int i = 0; i < 4; i++) {
    int i2 = t + 64 * i;
    double2 a = Rr[i2];
    double x0, x1;
    if (sec) { x0 = t1d[i2 * 2]; x1 = t1d[i2 * 2 + 1]; }
    else     { x0 = bv[i2 * 2];  x1 = bv[i2 * 2 + 1]; }
    acc += a.x * x0 + a.y * x1;
  }
  acc = wredD(acc);
  if (t == 0) { if (sec) y1[m] = acc; else y0[m] = acc; }
}

// t1d[m] = fp64 dot(A[m,:], v), 512 blocks x 256. [proven R6]
__global__ __launch_bounds__(256) void k_mv_A(const float* __restrict__ Mat,
                                              const float* __restrict__ v,
                                              double* __restrict__ t1d,
                                              const int* __restrict__ flag, int chk) {
  if (chk && *flag) return;
  const int m = blockIdx.x, tid = threadIdx.x;
  const float4* Mr = (const float4*)(Mat + (size_t)m * Ncols);
  const float4* v4 = (const float4*)v;
  double acc = 0.0;
#pragma unroll
  for (int i = 0; i < 4; i++) {
    float4 a = Mr[tid + 256 * i];
    float4 x = v4[tid + 256 * i];
    acc += (double)a.x * x.x + (double)a.y * x.y + (double)a.z * x.z + (double)a.w * x.w;
  }
  __shared__ double sb[4];
  acc = wredD(acc);
  const int lane = tid & 63, wid = tid >> 6;
  if (!lane) sb[wid] = acc;
  __syncthreads();
  if (!tid) t1d[m] = sb[0] + sb[1] + sb[2] + sb[3];
}

// ---------------------------------------------------------------------------
// R16(c): tail fold - last CG dv-update folded into the final A*dv matvec.
// 512 blocks x 256 thr. Every block replicates the dotbuf scalar reduce
// (vup_fin order); t1[m] = A[m,:] dot (dv + alpha p) in fp64; blocks 0..15
// write dv2 = dv + alpha p (disjoint slices; dv untouched -> race-free).
// flag set OR bad curvature -> alpha = 0 (matches old vup_fin semantics).
// ---------------------------------------------------------------------------
__global__ __launch_bounds__(256) void k_mv_A_up(const float* __restrict__ A,
                                                 const float* __restrict__ p_last,
                                                 const float* __restrict__ dv,
                                                 float* __restrict__ dv2,
                                                 const double* __restrict__ dotbuf,
                                                 const int* __restrict__ flag,
                                                 double* __restrict__ t1d) {
  __shared__ double sdd[20];
  __shared__ double sb[4];
  const int tid = threadIdx.x;
  const int lane = tid & 63, wid = tid >> 6;
  double alpha = 0.0;
  if (!(*flag)) {                       // uniform branch (same flag all lanes)
#pragma unroll
    for (int d = 0; d < 5; d++) {
      double v = dotbuf[d * 256 + tid];
      v = wredD(v);
      if (!lane) sdd[d * 4 + wid] = v;
    }
    __syncthreads();
    const double pPBp = sdd[0] + sdd[1] + sdd[2] + sdd[3];
    const double pp   = sdd[4] + sdd[5] + sdd[6] + sdd[7];
    const double rr   = sdd[16] + sdd[17] + sdd[18] + sdd[19];
    if (pPBp > 1e-6 * pp) alpha = rr / fmax(pPBp, 1e-300);
  }
  const int m = blockIdx.x;
  const float4* Mr = (const float4*)(A + (size_t)m * Ncols);
  const bool wb = (blockIdx.x < 16);
  double acc = 0.0;
#pragma unroll
  for (int i = 0; i < 4; i++) {
    const int i4 = tid + 256 * i;
    const float4 a  = Mr[i4];
    const float4 x  = ((const float4*)dv)[i4];
    const float4 pl = ((const float4*)p_last)[i4];
    const double x0 = (double)x.x + alpha * (double)pl.x;
    const double x1 = (double)x.y + alpha * (double)pl.y;
    const double x2 = (double)x.z + alpha * (double)pl.z;
    const double x3 = (double)x.w + alpha * (double)pl.w;
    acc += (double)a.x * x0 + (double)a.y * x1 + (double)a.z * x2 + (double)a.w * x3;
    if (wb && (i4 >> 6) == (int)blockIdx.x)
      ((float4*)dv2)[i4] = make_float4((float)x0, (float)x1, (float)x2, (float)x3);
  }
  acc = wredD(acc);
  if (!lane) sb[wid] = acc;
  __syncthreads();
  if (!tid) t1d[m] = sb[0] + sb[1] + sb[2] + sb[3];
}

// ---------------------------------------------------------------------------
// Bp = B p with the PREVIOUS iteration's CG update fused in (R11).
// 1024 blocks x 256 thr, 4 rows/block. When upd=1: every block replicates the
// k_vup scalar reduce from dotbuf (bitwise-identical order), computes p_new
// into its own LDS; blocks 0..15 write disjoint slices of p_cur/r_cur/dv.
// Ping-pong p/r buffers: readers only touch *_prev, writers only *_cur.
// ---------------------------------------------------------------------------
__global__ __launch_bounds__(256) void k_mv_B4u(const float* __restrict__ B,
                                                const float* __restrict__ p_prev,
                                                float* __restrict__ p_cur,
                                                const float* __restrict__ r_prev,
                                                float* __restrict__ r_cur,
                                                const float* __restrict__ PBp,
                                                const double* __restrict__ dotbuf,
                                                float* __restrict__ dv,
                                                float* __restrict__ Bp,
                                                int* __restrict__ flag, int upd) {
  if (flag[0]) return;
  __shared__ float4 ps[1024];
  __shared__ double sdd[20];
  const int tid = threadIdx.x;
  const int wid = tid >> 6, lane = tid & 63;
  if (!upd) {
#pragma unroll
    for (int l = 0; l < 4; l++)
      ps[tid + 256 * l] = ((const float4*)p_cur)[tid + 256 * l];
  } else {
#pragma unroll
    for (int d = 0; d < 5; d++) {
      double v = dotbuf[d * 256 + tid];
      v = wredD(v);
      if (!lane) sdd[d * 4 + wid] = v;
    }
    __syncthreads();
    double tot[5];
#pragma unroll
    for (int d = 0; d < 5; d++)
      tot[d] = sdd[d * 4] + sdd[d * 4 + 1] + sdd[d * 4 + 2] + sdd[d * 4 + 3];
    const double pPBp = tot[0], pp = tot[1], rPBp = tot[2], PBp2 = tot[3], rr = tot[4];
    if (pPBp <= 1e-6 * pp) { if (tid == 0) flag[0] = 1; return; }
    const double alpha = rr / fmax(pPBp, 1e-300);
    double rn2 = rr - 2.0 * alpha * rPBp + alpha * alpha * PBp2;
    rn2 = fmax(rn2, 0.0);
    const double beta = rn2 / fmax(rr, 1e-300);
    const bool wb = (blockIdx.x < 16);
#pragma unroll
    for (int l = 0; l < 4; l++) {
      const int i4 = tid + 256 * l;
      const float4 pv = ((const float4*)p_prev)[i4];
      const float4 rv = ((const float4*)r_prev)[i4];
      const float4 qv = ((const float4*)PBp)[i4];
      const double rd0 = (double)rv.x - alpha * (double)qv.x;
      const double rd1 = (double)rv.y - alpha * (double)qv.y;
      const double rd2 = (double)rv.z - alpha * (double)qv.z;
      const double rd3 = (double)rv.w - alpha * (double)qv.w;
      const float4 pn = make_float4((float)(rd0 + beta * (double)pv.x),
                                    (float)(rd1 + beta * (double)pv.y),
                                    (float)(rd2 + beta * (double)pv.z),
                                    (float)(rd3 + beta * (double)pv.w));
      ps[i4] = pn;
      if (wb && (i4 >> 6) == (int)blockIdx.x) {
        ((float4*)p_cur)[i4] = pn;
        ((float4*)r_cur)[i4] =
            make_float4((float)rd0, (float)rd1, (float)rd2, (float)rd3);
        float4 dvv = ((float4*)dv)[i4];
        dvv.x = (float)((double)dvv.x + alpha * (double)pv.x);
        dvv.y = (float)((double)dvv.y + alpha * (double)pv.y);
        dvv.z = (float)((double)dvv.z + alpha * (double)pv.z);
        dvv.w = (float)((double)dvv.w + alpha * (double)pv.w);
        ((float4*)dv)[i4] = dvv;
      }
    }
    if (rn2 < 1e-16) {  // converged: updates written, skip this matvec
      if (tid == 0 && blockIdx.x == 0) flag[0] = 1;
      return;
    }
  }
  __syncthreads();
  const int row = blockIdx.x * 4 + wid;
  const float4* Br = (const float4*)(B + (size_t)row * Ncols);
  double acc = 0.0;
#pragma unroll
  for (int i = 0; i < 16; i++) {
    const float4 a = Br[lane + 64 * i];
    const float4 x = ps[lane + 64 * i];
    acc += (double)a.x * x.x + (double)a.y * x.y + (double)a.z * x.z + (double)a.w * x.w;
  }
  acc = wredD(acc);
  if (!lane) Bp[row] = (float)acc;
}

// Setup outputs + CG init. [proven R6]
__global__ __launch_bounds__(256) void k_setup_fin(const float* __restrict__ A,
                                                   const double* __restrict__ y0d,
                                                   const double* __restrict__ y1d,
                                                   const float* __restrict__ g,
                                                   float* __restrict__ out,
                                                   float* __restrict__ r,
                                                   float* __restrict__ p,
                                                   float* __restrict__ dv) {
  __shared__ double y0s[512], y1s[512];
  const int tid = threadIdx.x;
  y0s[tid] = y0d[tid]; y0s[tid + 256] = y0d[tid + 256];
  y1s[tid] = y1d[tid]; y1s[tid + 256] = y1d[tid + 256];
  __syncthreads();
  const int col = blockIdx.x * 256 + tid;
  double xa = 0.0, ra = 0.0;
  for (int m = 0; m < Mrows; m++) {
    double av = (double)A[(size_t)m * Ncols + col];
    xa += av * y0s[m];
    ra += av * y1s[m];
  }
  out[col] = (float)xa;
  float rv = (float)(ra - (double)g[col]);
  r[col] = rv; p[col] = rv; dv[col] = 0.f;
}

// ---------------------------------------------------------------------------
// PBp = Bp - A^T y ; fresh fp64 dots {p.PBp, p.p, r.PBp, PBp.PBp, r.r}
// -> dotbuf[d*256 + bid]. 256 blocks x 256 thr, 16 cols/block, m 16-split.
// ---------------------------------------------------------------------------
__global__ __launch_bounds__(256) void k_pcc3(const float* __restrict__ A,
                                              const double* __restrict__ yd,
                                              const float* __restrict__ Bp,
                                              const float* __restrict__ p,
                                              const float* __restrict__ r,
                                              float* __restrict__ PBp,
                                              double* __restrict__ dotbuf,
                                              const int* __restrict__ flag) {
  if (*flag) return;
  __shared__ double ysh[512];
  __shared__ double part[256];
  __shared__ double d5[80];
  const int tid = threadIdx.x;
  ysh[tid] = yd[tid]; ysh[tid + 256] = yd[tid + 256];
  __syncthreads();
  const int cl = tid & 15, ms = tid >> 4;
  const int col = blockIdx.x * 16 + cl;
  double acc = 0.0;
  for (int m = ms * 32; m < ms * 32 + 32; m++)
    acc += (double)A[(size_t)m * Ncols + col] * ysh[m];
  part[ms * 16 + cl] = acc;
  __syncthreads();
  if (tid < 16) {
    const int c = blockIdx.x * 16 + tid;
    double s = 0.0;
#pragma unroll
    for (int q = 0; q < 16; q++) s += part[q * 16 + tid];
    const double pb = (double)Bp[c] - s;
    PBp[c] = (float)pb;
    const double pi = (double)p[c];
    const double ri = (double)r[c];
    d5[0 * 16 + tid] = pi * pb;
    d5[1 * 16 + tid] = pi * pi;
    d5[2 * 16 + tid] = ri * pb;
    d5[3 * 16 + tid] = pb * pb;
    d5[4 * 16 + tid] = ri * ri;
  }
  __syncthreads();
  if (tid < 5) {
    double s = 0.0;
#pragma unroll
    for (int c = 0; c < 16; c++) s += d5[tid * 16 + c];
    dotbuf[tid * 256 + blockIdx.x] = s;
  }
}

// out[4096+col] = dv2[col] - (A^T yd)[col]. [proven R6; R16(c): reads dv2]
__global__ __launch_bounds__(256) void k_final_d(const float* __restrict__ A,
                                                 const double* __restrict__ yd,
                                                 const float* __restrict__ dv2,
                                                 float* __restrict__ out) {
  __shared__ double ysm[512];
  const int tid = threadIdx.x;
  ysm[tid] = yd[tid]; ysm[tid + 256] = yd[tid + 256];
  __syncthreads();
  const int col = blockIdx.x * 256 + tid;
  double acc = 0.0;
  for (int m = 0; m < Mrows; m++) acc += (double)A[(size_t)m * Ncols + col] * ysm[m];
  out[Ncols + col] = (float)((double)dv2[col] - acc);
}

// ---------------------------------------------------------------------------
extern "C" void kernel_launch(void* const* d_in, const int* in_sizes, int n_in,
                              void* d_out, int out_size, void* d_ws, size_t ws_size,
                              hipStream_t stream) {
  const float* A = (const float*)d_in[0];   // 512 x 4096
  const float* b = (const float*)d_in[1];   // 512
  const float* B = (const float*)d_in[2];   // 4096 x 4096
  const float* g = (const float*)d_in[3];   // 4096
  float* out = (float*)d_out;               // x[4096] then d[4096]
  float* ws = (float*)d_ws;

  // NOTE aliasing is ordering-safe: aat writes P[0..31] (ws+1048576 ..
  // ws+9437184 floats) FIRST; redG consumes; all later buffers in that range
  // are written after aat+redG complete.
  float*  G   = ws;                         // 262144 floats
  float*  Xa  = ws + 262144;
  float*  Xb  = ws + 524288;
  float*  P   = ws + 1048576;               // 32 x 262144 (AAT) / 8 (NS)
  double* Ed  = (double*)(ws + 1048576);    // aliases P (used after NS only)
  double* Ud  = (double*)(ws + 1572864);    // aliases P
  double* Rd  = (double*)(ws + 3145728);    // 512x512 fp64
  float*  Bp  = ws + 3670016;               // 4096 each
  float*  PBp = ws + 3674112;
  float*  r   = ws + 3678208;
  float*  p   = ws + 3682304;
  float*  dv  = ws + 3686400;
  double* t1d = (double*)(ws + 3690496);    // 512 doubles
  double* y0d = (double*)(ws + 3691520);
  double* y1d = (double*)(ws + 3692544);
  double* dotbuf = (double*)(ws + 3693568); // 5 x 256 doubles
  int*    flag   = (int*)(ws + 3696132);
  float*  p2  = ws + 3696144;               // ping-pong partners (R11)
  float*  r2  = ws + 3700240;
  float*  dv2 = ws + 3704336;               // R16(c) final-dv ping-pong

  // --- G = A A^T (32 K-slices, 128^2 tiles, 8x8/thread) ; row-reduce ---
  k_aat_part<<<dim3(4, 4, 32), 256, 0, stream>>>(A, P);
  k_redG<<<Mrows, 64, 0, stream>>>(P, G);

  // --- X0 = c0 I + c1 G + c2 G^2 (degree-2 Chebyshev) ---
  k_ns_a<<<dim3(8, 8, 4), 256, 0, stream>>>(G, G, P);          // P[0..3] = G*G
  k_init2s<<<256, 256, 0, stream>>>(Xa, G, P, flag);

  // --- Newton-Schulz: X' = 2X - X(GX), 2 iters, 3 kernels each ---
  float* Xcur = Xa;
  float* Xnxt = Xb;
  for (int it = 0; it < 2; it++) {
    k_ns_a<<<dim3(8, 8, 4), 256, 0, stream>>>(G, Xcur, P);      // P[0..3] = G*X
    k_ns_b<<<dim3(8, 8, 4), 256, 0, stream>>>(Xcur, P, P + 4 * 262144);  // P[4..7] = X*T
    k_ns_c<<<256, 256, 0, stream>>>(Xcur, P, Xnxt);             // Xn = 2X - sum
    float* tmp = Xcur; Xcur = Xnxt; Xnxt = tmp;
  }

  // --- R = X (I+E+E^2), E = I - G X : G*R = I - E^3 (fp64) ---
  k_gemm_E<<<dim3(16, 16), 256, 0, stream>>>(G, Xcur, Ed);
  k_gemm_XE<<<dim3(16, 16), 256, 0, stream>>>(Xcur, Ed, Ud);
  k_gemm_UER<<<dim3(16, 16), 256, 0, stream>>>(Ud, Ed, Xcur, Rd);

  // --- x = A^T R b ; r0 = p = A^T R (A g) - g  (R16(b): merged solveRs) ---
  k_mv_A<<<Mrows, 256, 0, stream>>>(A, g, t1d, flag, 0);
  k_solveR2<<<2 * Mrows, 64, 0, stream>>>(Rd, b, t1d, y0d, y1d);
  k_setup_fin<<<16, 256, 0, stream>>>(A, y0d, y1d, g, out, r, p, dv);

  // --- projected CG, CG_ITERS iterations, 4 launches/iter ---
  float* pb[2] = {p, p2};
  float* rb[2] = {r, r2};
  for (int it = 0; it < CG_ITERS; it++) {
    const int cur = it & 1, prv = cur ^ 1;
    if (it == 0)
      k_mv_B4u<<<1024, 256, 0, stream>>>(B, pb[0], pb[0], rb[0], rb[0], PBp,
                                         dotbuf, dv, Bp, flag, 0);
    else
      k_mv_B4u<<<1024, 256, 0, stream>>>(B, pb[prv], pb[cur], rb[prv], rb[cur],
                                         PBp, dotbuf, dv, Bp, flag, 1);
    k_mv_A<<<Mrows, 256, 0, stream>>>(A, Bp, t1d, flag, 1);
    k_solveR<<<Mrows, 64, 0, stream>>>(Rd, (const float*)0, t1d, y1d, flag, 1);
    k_pcc3<<<256, 256, 0, stream>>>(A, y1d, Bp, pb[cur], rb[cur], PBp, dotbuf, flag);
  }

  // --- d_out = P(dv + alpha p_last): fold + strip row-space (R16(c)) ---
  k_mv_A_up<<<Mrows, 256, 0, stream>>>(A, pb[(CG_ITERS - 1) & 1], dv, dv2,
                                       dotbuf, flag, t1d);
  k_solveR<<<Mrows, 64, 0, stream>>>(Rd, (const float*)0, t1d, y1d, flag, 0);
  k_final_d<<<16, 256, 0, stream>>>(A, y1d, dv2, out);
}

// Round 12
// 428.755 us; speedup vs baseline: 1.1721x; 1.0634x over previous
//
#include <hip/hip_runtime.h>
#include <hip/hip_bf16.h>

// ProjectedCGCraig on MI355X (gfx950).
//   x = A^T G^{-1} b,  G = A A^T (512x512)
//   d = projected CG with P v = v - A^T G^{-1} A v
// LESSON (R3): per-iteration projection must be refinement-exact (<=1e-9).
// LESSON (R5): CG scalars MEASURED fresh from stored fp32 vectors each iter.
// LESSON (R7): grid.sync() ~28us; launches (~2.2us) are the cheap grid sync.
// LESSON (R9->R10): LAST-BLOCK-ticket fold REGRESSED ~+100us. Launch
//   boundary IS the cheap handoff; replicated-reduce + disjoint-slice
//   writes + ping-pong buffers is the SAFE fold pattern (proven R11).
// LESSON (R14->R15): LDS row pad must keep rows 16B-ALIGNED. Pad 132.
// LESSON (R8-R10 submit): exactly ONE fence pair per reply, no stray
//   backtick runs anywhere (prose or comments).
// LESSON (R16->R17, counters): fp64 32x32-tile GEMMs are latency-bound
//   crawlers (k_gemm_UER 40us, VALUBusy 8.7%, 1 blk/CU). Only E = I - GX
//   has CANCELLATION (O(1) sums -> 3.5e-4 entries); U = X*E and V = U*E
//   are cancellation-free -> fp32 abs err 3.5e-10 < 1e-9 requirement.
// R17 (this round): refinement = 1 fp64 GEMM (E, + fused Ef=float(E))
//   + fp32 U-partials (k_ns_a) + fp32 V-partials (k_uef) + k_Rasm
//   (R = X + sumPU + sumPV, fp64). Drops k_gemm_XE/k_gemm_UER (~75us)
//   for ~30us of fp32 work.
// R16: aat single-buffer 33.8KB (co-residency fixed); solveR2 head merge;
//   k_mv_A_up tail fold. R11: k_mv_B4u fused CG update. R12-R14: degree-2
//   Chebyshev init on [0.35,2.0], NS=2, CG=5.
// M=512, N=4096 fixed.

#define Mrows 512
#define Ncols 4096
#define CG_ITERS 5
#define AAT_PAD 132

__device__ __forceinline__ double wredD(double v) {
#pragma unroll
  for (int off = 32; off; off >>= 1) v += __shfl_down(v, off, 64);
  return v;
}

// ---------------------------------------------------------------------------
// Partial AAT: slice bz = A[bi..+128][Kb..+128] * A[bj..+128][..]^T.
// grid (4,4,32), 256 thr, 8x8 micro-tile, single-buffer LDS 33.8KB. [R16]
// ---------------------------------------------------------------------------
__global__ __launch_bounds__(256) void k_aat_part(const float* __restrict__ A,
                                                  float* __restrict__ P) {
  __shared__ __align__(16) float At[32][AAT_PAD];
  __shared__ __align__(16) float Bt[32][AAT_PAD];
  const int tid = threadIdx.x;
  const int tx = tid & 15, ty = tid >> 4;
  const int bj = blockIdx.x * 128, bi = blockIdx.y * 128;
  const int Kb = blockIdx.z * 128;
  const int ar = tid >> 3, ak = tid & 7;
  const int ak4 = ak * 4, ty4 = ty * 4, tx4 = tx * 4;
  const float* pa0 = &A[(size_t)(bi + ar) * Ncols + Kb + ak4];
  const float* pa1 = pa0 + (size_t)32 * Ncols;
  const float* pa2 = pa0 + (size_t)64 * Ncols;
  const float* pa3 = pa0 + (size_t)96 * Ncols;
  const float* pb0 = &A[(size_t)(bj + ar) * Ncols + Kb + ak4];
  const float* pb1 = pb0 + (size_t)32 * Ncols;
  const float* pb2 = pb0 + (size_t)64 * Ncols;
  const float* pb3 = pb0 + (size_t)96 * Ncols;
  float4 ra0 = *(const float4*)pa0, ra1 = *(const float4*)pa1;
  float4 ra2 = *(const float4*)pa2, ra3 = *(const float4*)pa3;
  float4 rb0 = *(const float4*)pb0, rb1 = *(const float4*)pb1;
  float4 rb2 = *(const float4*)pb2, rb3 = *(const float4*)pb3;
  float4 c[8][2];
#pragma unroll
  for (int i = 0; i < 8; i++) {
    c[i][0] = make_float4(0.f, 0.f, 0.f, 0.f);
    c[i][1] = make_float4(0.f, 0.f, 0.f, 0.f);
  }
  for (int s = 0; s < 4; ++s) {
    if (s) __syncthreads();
    At[ak4 + 0][ar] = ra0.x; At[ak4 + 1][ar] = ra0.y;
    At[ak4 + 2][ar] = ra0.z; At[ak4 + 3][ar] = ra0.w;
    At[ak4 + 0][ar + 32] = ra1.x; At[ak4 + 1][ar + 32] = ra1.y;
    At[ak4 + 2][ar + 32] = ra1.z; At[ak4 + 3][ar + 32] = ra1.w;
    At[ak4 + 0][ar + 64] = ra2.x; At[ak4 + 1][ar + 64] = ra2.y;
    At[ak4 + 2][ar + 64] = ra2.z; At[ak4 + 3][ar + 64] = ra2.w;
    At[ak4 + 0][ar + 96] = ra3.x; At[ak4 + 1][ar + 96] = ra3.y;
    At[ak4 + 2][ar + 96] = ra3.z; At[ak4 + 3][ar + 96] = ra3.w;
    Bt[ak4 + 0][ar] = rb0.x; Bt[ak4 + 1][ar] = rb0.y;
    Bt[ak4 + 2][ar] = rb0.z; Bt[ak4 + 3][ar] = rb0.w;
    Bt[ak4 + 0][ar + 32] = rb1.x; Bt[ak4 + 1][ar + 32] = rb1.y;
    Bt[ak4 + 2][ar + 32] = rb1.z; Bt[ak4 + 3][ar + 32] = rb1.w;
    Bt[ak4 + 0][ar + 64] = rb2.x; Bt[ak4 + 1][ar + 64] = rb2.y;
    Bt[ak4 + 2][ar + 64] = rb2.z; Bt[ak4 + 3][ar + 64] = rb2.w;
    Bt[ak4 + 0][ar + 96] = rb3.x; Bt[ak4 + 1][ar + 96] = rb3.y;
    Bt[ak4 + 2][ar + 96] = rb3.z; Bt[ak4 + 3][ar + 96] = rb3.w;
    __syncthreads();
    if (s < 3) {
      const int off = (s + 1) * 32;
      ra0 = *(const float4*)(pa0 + off); ra1 = *(const float4*)(pa1 + off);
      ra2 = *(const float4*)(pa2 + off); ra3 = *(const float4*)(pa3 + off);
      rb0 = *(const float4*)(pb0 + off); rb1 = *(const float4*)(pb1 + off);
      rb2 = *(const float4*)(pb2 + off); rb3 = *(const float4*)(pb3 + off);
    }
#pragma unroll
    for (int kk = 0; kk < 32; kk++) {
      const float4 a0 = *(const float4*)&At[kk][ty4];
      const float4 a1 = *(const float4*)&At[kk][64 + ty4];
      const float4 b0 = *(const float4*)&Bt[kk][tx4];
      const float4 b1 = *(const float4*)&Bt[kk][64 + tx4];
      const float av[8] = {a0.x, a0.y, a0.z, a0.w, a1.x, a1.y, a1.z, a1.w};
#pragma unroll
      for (int i = 0; i < 8; i++) {
        c[i][0].x += av[i] * b0.x; c[i][0].y += av[i] * b0.y;
        c[i][0].z += av[i] * b0.z; c[i][0].w += av[i] * b0.w;
        c[i][1].x += av[i] * b1.x; c[i][1].y += av[i] * b1.y;
        c[i][1].z += av[i] * b1.z; c[i][1].w += av[i] * b1.w;
      }
    }
  }
  float* Co = P + (size_t)blockIdx.z * 262144;
#pragma unroll
  for (int i = 0; i < 8; i++) {
    const int row = bi + ((i < 4) ? (ty4 + i) : (64 + ty4 + (i - 4)));
    const size_t o = (size_t)row * Mrows + bj;
    *(float4*)&Co[o + tx4]      = c[i][0];
    *(float4*)&Co[o + 64 + tx4] = c[i][1];
  }
}

// G row = sum of 32 AAT partials. 512 blocks x 64 thr.
__global__ __launch_bounds__(64) void k_redG(const float* __restrict__ P,
                                             float* __restrict__ G) {
  const int row = blockIdx.x, lane = threadIdx.x;
#pragma unroll
  for (int j = 0; j < 2; j++) {
    const int i4 = row * 128 + lane + 64 * j;
    float4 s = ((const float4*)P)[i4];
#pragma unroll
    for (int q = 1; q < 32; q++) {
      const float4 v = ((const float4*)(P + (size_t)q * 262144))[i4];
      s.x += v.x; s.y += v.y; s.z += v.z; s.w += v.w;
    }
    ((float4*)G)[i4] = s;
  }
}

// ---------------------------------------------------------------------------
// X0 = c0 I + c1 G + c2 G^2 : degree-2 Chebyshev p(lambda) ~ 1/lambda on
// [0.35, 2.0]. E0 = 1/T3(1.4242) = 0.13730. G^2 partials from k_ns_a(G,G,P).
// ---------------------------------------------------------------------------
__global__ void k_init2s(float* __restrict__ X, const float* __restrict__ G,
                         const float* __restrict__ P, int* __restrict__ flag) {
  const float c0 = 3.5517450f;
  const float c1 = -3.4476528f;
  const float c2 = 0.9780600f;
  const int i4 = blockIdx.x * 256 + threadIdx.x;  // 0..65535
  float4 s = ((const float4*)P)[i4];
#pragma unroll
  for (int q = 1; q < 4; q++) {
    const float4 v = ((const float4*)(P + (size_t)q * 262144))[i4];
    s.x += v.x; s.y += v.y; s.z += v.z; s.w += v.w;
  }
  const float4 g4 = ((const float4*)G)[i4];
  const int e0 = i4 * 4;
  const int row = e0 >> 9, cb = e0 & 511;
  float4 xv;
  xv.x = c2 * s.x + c1 * g4.x + ((cb + 0) == row ? c0 : 0.f);
  xv.y = c2 * s.y + c1 * g4.y + ((cb + 1) == row ? c0 : 0.f);
  xv.z = c2 * s.z + c1 * g4.z + ((cb + 2) == row ? c0 : 0.f);
  xv.w = c2 * s.w + c1 * g4.w + ((cb + 3) == row ? c0 : 0.f);
  ((float4*)X)[i4] = xv;
  if (i4 == 0) { flag[0] = 0; flag[1] = 0; }
}

// ---------------------------------------------------------------------------
// NS (a) / generic fp32 partial GEMM: P[0..3] = Aop * Bop partials.
// grid (8,8,4), K-slice 128, 256 thr. Used for G*X, G*G, and X*Ef (R17).
// ---------------------------------------------------------------------------
__global__ __launch_bounds__(256) void k_ns_a(const float* __restrict__ G,
                                              const float* __restrict__ Xc,
                                              float* __restrict__ P) {
  __shared__ float At[2][32][68];
  __shared__ float Bt[2][32][68];
  const int tid = threadIdx.x;
  const int tx = tid & 15, ty = tid >> 4;
  const int bj = blockIdx.x * 64, bi = blockIdx.y * 64;
  const int Kb = blockIdx.z * 128;
  const int ar = tid >> 3, ak = tid & 7;
  const int br = tid >> 4, bc = tid & 15;
  const int ak4 = ak * 4, ty4 = ty * 4, tx4 = tx * 4, bc4 = bc * 4;
  const float* pa0 = &G[(size_t)(bi + ar) * Mrows + Kb + ak4];
  const float* pa1 = pa0 + (size_t)32 * Mrows;
  const float* pb0 = &Xc[(size_t)(Kb + br) * Mrows + bj + bc4];
  const float* pb1 = pb0 + (size_t)16 * Mrows;
  float4 ra0 = *(const float4*)pa0, ra1 = *(const float4*)pa1;
  float4 rb0 = *(const float4*)pb0, rb1 = *(const float4*)pb1;
  float c0x = 0.f, c0y = 0.f, c0z = 0.f, c0w = 0.f;
  float c1x = 0.f, c1y = 0.f, c1z = 0.f, c1w = 0.f;
  float c2x = 0.f, c2y = 0.f, c2z = 0.f, c2w = 0.f;
  float c3x = 0.f, c3y = 0.f, c3z = 0.f, c3w = 0.f;
  for (int s = 0; s < 4; ++s) {
    float (*Atc)[68] = At[s & 1];
    float (*Btc)[68] = Bt[s & 1];
    Atc[ak4 + 0][ar] = ra0.x; Atc[ak4 + 1][ar] = ra0.y;
    Atc[ak4 + 2][ar] = ra0.z; Atc[ak4 + 3][ar] = ra0.w;
    Atc[ak4 + 0][ar + 32] = ra1.x; Atc[ak4 + 1][ar + 32] = ra1.y;
    Atc[ak4 + 2][ar + 32] = ra1.z; Atc[ak4 + 3][ar + 32] = ra1.w;
    *(float4*)&Btc[br][bc4]      = rb0;
    *(float4*)&Btc[br + 16][bc4] = rb1;
    __syncthreads();
    if (s < 3) {
      const int offA = (s + 1) * 32;
      const size_t offB = (size_t)(s + 1) * 32 * Mrows;
      ra0 = *(const float4*)(pa0 + offA); ra1 = *(const float4*)(pa1 + offA);
      rb0 = *(const float4*)(pb0 + offB); rb1 = *(const float4*)(pb1 + offB);
    }
#pragma unroll
    for (int kk = 0; kk < 32; kk++) {
      float4 a = *(float4*)&Atc[kk][ty4];
      float4 b = *(float4*)&Btc[kk][tx4];
      c0x += a.x * b.x; c0y += a.x * b.y; c0z += a.x * b.z; c0w += a.x * b.w;
      c1x += a.y * b.x; c1y += a.y * b.y; c1z += a.y * b.z; c1w += a.y * b.w;
      c2x += a.z * b.x; c2y += a.z * b.y; c2z += a.z * b.z; c2w += a.z * b.w;
      c3x += a.w * b.x; c3y += a.w * b.y; c3z += a.w * b.z; c3w += a.w * b.w;
    }
  }
  float* Co = P + (size_t)blockIdx.z * 262144;
  size_t o = (size_t)(bi + ty4) * Mrows + bj + tx4;
  *(float4*)&Co[o]             = make_float4(c0x, c0y, c0z, c0w);
  *(float4*)&Co[o + Mrows]     = make_float4(c1x, c1y, c1z, c1w);
  *(float4*)&Co[o + 2 * Mrows] = make_float4(c2x, c2y, c2z, c2w);
  *(float4*)&Co[o + 3 * Mrows] = make_float4(c3x, c3y, c3z, c3w);
}

// ---------------------------------------------------------------------------
// NS (b): P[4..7] = Xc * T partials, T = sum(P[0..3]) folded into B-staging.
// grid (8,8,4). [fold logic proven R7]
// ---------------------------------------------------------------------------
__global__ __launch_bounds__(256) void k_ns_b(const float* __restrict__ Xc,
                                              const float* __restrict__ P,
                                              float* __restrict__ Pout) {
  __shared__ float At[32][68];
  __shared__ float Bt[32][68];
  const int tid = threadIdx.x;
  const int tx = tid & 15, ty = tid >> 4;
  const int bj = blockIdx.x * 64, bi = blockIdx.y * 64;
  const int Kb = blockIdx.z * 128;
  float c0x = 0.f, c0y = 0.f, c0z = 0.f, c0w = 0.f;
  float c1x = 0.f, c1y = 0.f, c1z = 0.f, c1w = 0.f;
  float c2x = 0.f, c2y = 0.f, c2z = 0.f, c2w = 0.f;
  float c3x = 0.f, c3y = 0.f, c3z = 0.f, c3w = 0.f;
  for (int k0 = 0; k0 < 128; k0 += 32) {
#pragma unroll
    for (int l = 0; l < 2; l++) {
      int f = tid + l * 256;
      int ar = f >> 3, ak = f & 7;
      const float4 av = *(const float4*)&Xc[(size_t)(bi + ar) * Mrows + Kb + k0 + ak * 4];
      At[ak * 4 + 0][ar] = av.x; At[ak * 4 + 1][ar] = av.y;
      At[ak * 4 + 2][ar] = av.z; At[ak * 4 + 3][ar] = av.w;
      int br = f >> 4, bc = f & 15;
      const size_t bo = (size_t)(Kb + k0 + br) * Mrows + bj + bc * 4;
      float4 bs = *(const float4*)&P[bo];
#pragma unroll
      for (int q = 1; q < 4; q++) {
        const float4 v = *(const float4*)&P[bo + (size_t)q * 262144];
        bs.x += v.x; bs.y += v.y; bs.z += v.z; bs.w += v.w;
      }
      *(float4*)&Bt[br][bc * 4] = bs;
    }
    __syncthreads();
#pragma unroll
    for (int kk = 0; kk < 32; kk++) {
      float4 a = *(float4*)&At[kk][ty * 4];
      float4 b = *(float4*)&Bt[kk][tx * 4];
      c0x += a.x * b.x; c0y += a.x * b.y; c0z += a.x * b.z; c0w += a.x * b.w;
      c1x += a.y * b.x; c1y += a.y * b.y; c1z += a.y * b.z; c1w += a.y * b.w;
      c2x += a.z * b.x; c2y += a.z * b.y; c2z += a.z * b.z; c2w += a.z * b.w;
      c3x += a.w * b.x; c3y += a.w * b.y; c3z += a.w * b.z; c3w += a.w * b.w;
    }
    __syncthreads();
  }
  float* Co = Pout + (size_t)blockIdx.z * 262144;
  size_t o = (size_t)(bi + ty * 4) * Mrows + bj + tx * 4;
  *(float4*)&Co[o]             = make_float4(c0x, c0y, c0z, c0w);
  *(float4*)&Co[o + Mrows]     = make_float4(c1x, c1y, c1z, c1w);
  *(float4*)&Co[o + 2 * Mrows] = make_float4(c2x, c2y, c2z, c2w);
  *(float4*)&Co[o + 3 * Mrows] = make_float4(c3x, c3y, c3z, c3w);
}

// NS (c): Xn = 2*Xc - sum(P[4..7]). 256 blocks x 256 thr (float4 each).
__global__ void k_ns_c(const float* __restrict__ Xc, const float* __restrict__ P,
                       float* __restrict__ Xn) {
  const int i4 = blockIdx.x * 256 + threadIdx.x;
  float4 s = ((const float4*)(P + (size_t)4 * 262144))[i4];
#pragma unroll
  for (int q = 5; q < 8; q++) {
    const float4 v = ((const float4*)(P + (size_t)q * 262144))[i4];
    s.x += v.x; s.y += v.y; s.z += v.z; s.w += v.w;
  }
  const float4 xc = ((const float4*)Xc)[i4];
  ((float4*)Xn)[i4] = make_float4(2.f * xc.x - s.x, 2.f * xc.y - s.y,
                                  2.f * xc.z - s.z, 2.f * xc.w - s.w);
}

// ---------------------------------------------------------------------------
// E = I - G X, fp64 accumulation (the ONLY cancellation-sensitive GEMM).
// Also emits Ef = float(E) for the fp32 correction GEMMs (R17).
// ---------------------------------------------------------------------------
__global__ __launch_bounds__(256) void k_gemm_E(const float* __restrict__ G,
                                                const float* __restrict__ X,
                                                double* __restrict__ E,
                                                float* __restrict__ Ef) {
  __shared__ float Gs[32][33], Xs[32][33];
  const int tid = threadIdx.x;
  const int tx = tid & 15, ty = tid >> 4;
  const int bi = blockIdx.y * 32, bj = blockIdx.x * 32;
  const int r0 = ty * 2, c0 = tx * 2;
  double a00 = 0, a01 = 0, a10 = 0, a11 = 0;
  for (int k0 = 0; k0 < Mrows; k0 += 32) {
#pragma unroll
    for (int l = 0; l < 4; l++) {
      int e = tid + l * 256;
      int rr = e >> 5, cc = e & 31;
      Gs[rr][cc] = G[(size_t)(bi + rr) * Mrows + k0 + cc];
      Xs[rr][cc] = X[(size_t)(k0 + rr) * Mrows + bj + cc];
    }
    __syncthreads();
#pragma unroll
    for (int kk = 0; kk < 32; kk++) {
      double g0 = Gs[r0][kk], g1 = Gs[r0 + 1][kk];
      double x0 = Xs[kk][c0], x1 = Xs[kk][c0 + 1];
      a00 += g0 * x0; a01 += g0 * x1; a10 += g1 * x0; a11 += g1 * x1;
    }
    __syncthreads();
  }
  size_t o = (size_t)(bi + r0) * Mrows + bj + c0;
  const double e00 = ((bi + r0) == (bj + c0) ? 1.0 : 0.0) - a00;
  const double e01 = ((bi + r0) == (bj + c0 + 1) ? 1.0 : 0.0) - a01;
  const double e10 = ((bi + r0 + 1) == (bj + c0) ? 1.0 : 0.0) - a10;
  const double e11 = ((bi + r0 + 1) == (bj + c0 + 1) ? 1.0 : 0.0) - a11;
  E[o] = e00; E[o + 1] = e01; E[o + Mrows] = e10; E[o + Mrows + 1] = e11;
  Ef[o] = (float)e00; Ef[o + 1] = (float)e01;
  Ef[o + Mrows] = (float)e10; Ef[o + Mrows + 1] = (float)e11;
}

// ---------------------------------------------------------------------------
// R17: V-partials = U * Ef, where U = sum(PU[0..3]) folded into A-staging
// (k_ns_b mirror: fold on A side, plain B = Ef). grid (8,8,4).
// ---------------------------------------------------------------------------
__global__ __launch_bounds__(256) void k_uef(const float* __restrict__ PU,
                                             const float* __restrict__ Ef,
                                             float* __restrict__ PV) {
  __shared__ float At[32][68];
  __shared__ float Bt[32][68];
  const int tid = threadIdx.x;
  const int tx = tid & 15, ty = tid >> 4;
  const int bj = blockIdx.x * 64, bi = blockIdx.y * 64;
  const int Kb = blockIdx.z * 128;
  float c0x = 0.f, c0y = 0.f, c0z = 0.f, c0w = 0.f;
  float c1x = 0.f, c1y = 0.f, c1z = 0.f, c1w = 0.f;
  float c2x = 0.f, c2y = 0.f, c2z = 0.f, c2w = 0.f;
  float c3x = 0.f, c3y = 0.f, c3z = 0.f, c3w = 0.f;
  for (int k0 = 0; k0 < 128; k0 += 32) {
#pragma unroll
    for (int l = 0; l < 2; l++) {
      int f = tid + l * 256;
      int ar = f >> 3, ak = f & 7;
      const size_t ao = (size_t)(bi + ar) * Mrows + Kb + k0 + ak * 4;
      float4 as = *(const float4*)&PU[ao];
#pragma unroll
      for (int q = 1; q < 4; q++) {
        const float4 v = *(const float4*)&PU[ao + (size_t)q * 262144];
        as.x += v.x; as.y += v.y; as.z += v.z; as.w += v.w;
      }
      At[ak * 4 + 0][ar] = as.x; At[ak * 4 + 1][ar] = as.y;
      At[ak * 4 + 2][ar] = as.z; At[ak * 4 + 3][ar] = as.w;
      int br = f >> 4, bc = f & 15;
      *(float4*)&Bt[br][bc * 4] =
          *(const float4*)&Ef[(size_t)(Kb + k0 + br) * Mrows + bj + bc * 4];
    }
    __syncthreads();
#pragma unroll
    for (int kk = 0; kk < 32; kk++) {
      float4 a = *(float4*)&At[kk][ty * 4];
      float4 b = *(float4*)&Bt[kk][tx * 4];
      c0x += a.x * b.x; c0y += a.x * b.y; c0z += a.x * b.z; c0w += a.x * b.w;
      c1x += a.y * b.x; c1y += a.y * b.y; c1z += a.y * b.z; c1w += a.y * b.w;
      c2x += a.z * b.x; c2y += a.z * b.y; c2z += a.z * b.z; c2w += a.z * b.w;
      c3x += a.w * b.x; c3y += a.w * b.y; c3z += a.w * b.z; c3w += a.w * b.w;
    }
    __syncthreads();
  }
  float* Co = PV + (size_t)blockIdx.z * 262144;
  size_t o = (size_t)(bi + ty * 4) * Mrows + bj + tx * 4;
  *(float4*)&Co[o]             = make_float4(c0x, c0y, c0z, c0w);
  *(float4*)&Co[o + Mrows]     = make_float4(c1x, c1y, c1z, c1w);
  *(float4*)&Co[o + 2 * Mrows] = make_float4(c2x, c2y, c2z, c2w);
  *(float4*)&Co[o + 3 * Mrows] = make_float4(c3x, c3y, c3z, c3w);
}

// R17: R = X + sum(PU) + sum(PV), fp64 out. 256 blocks x 256 thr.
__global__ void k_Rasm(const float* __restrict__ Xf, const float* __restrict__ PU,
                       const float* __restrict__ PV, double* __restrict__ R) {
  const int i4 = blockIdx.x * 256 + threadIdx.x;  // 0..65535 float4 groups
  const float4 x = ((const float4*)Xf)[i4];
  double u0 = 0, u1 = 0, u2 = 0, u3 = 0;
#pragma unroll
  for (int q = 0; q < 4; q++) {
    const float4 uu = ((const float4*)(PU + (size_t)q * 262144))[i4];
    const float4 vv = ((const float4*)(PV + (size_t)q * 262144))[i4];
    u0 += (double)uu.x + (double)vv.x;
    u1 += (double)uu.y + (double)vv.y;
    u2 += (double)uu.z + (double)vv.z;
    u3 += (double)uu.w + (double)vv.w;
  }
  const size_t o = (size_t)i4 * 4;
  R[o]     = (double)x.x + u0;
  R[o + 1] = (double)x.y + u1;
  R[o + 2] = (double)x.z + u2;
  R[o + 3] = (double)x.w + u3;
}

// y = R * rhs (fp64 matvec, 512 blocks x 64 thr). [proven R6]
__global__ __launch_bounds__(64) void k_solveR(const double* __restrict__ R,
                                               const float* __restrict__ rhs_f,
                                               const double* __restrict__ rhs_d,
                                               double* __restrict__ y,
                                               const int* __restrict__ flag, int chk) {
  if (chk && *flag) return;
  const int m = blockIdx.x, t = threadIdx.x;
  const double2* Rr = (const double2*)(R + (size_t)m * Mrows);
  double acc = 0.0;
#pragma unroll
  for (int i = 0; i < 4; i++) {
    int i2 = t + 64 * i;
    double2 a = Rr[i2];
    double x0, x1;
    if (rhs_f) { x0 = rhs_f[i2 * 2]; x1 = rhs_f[i2 * 2 + 1]; }
    else       { x0 = rhs_d[i2 * 2]; x1 = rhs_d[i2 * 2 + 1]; }
    acc += a.x * x0 + a.y * x1;
  }
  acc = wredD(acc);
  if (t == 0) y[m] = acc;
}

// R16(b): head merge - 1024 blocks: [0,512) y0 = R b ; [512,1024) y1 = R t1d.
__global__ __launch_bounds__(64) void k_solveR2(const double* __restrict__ R,
                                                const float* __restrict__ bv,
                                                const double* __restrict__ t1d,
                                                double* __restrict__ y0,
                                                double* __restrict__ y1) {
  const int m = blockIdx.x & 511;
  const int sec = blockIdx.x >> 9;
  const int t = threadIdx.x;
  const double2* Rr = (const double2*)(R + (size_t)m * Mrows);
  double acc = 0.0;
#pragma unroll
  for (int i = 0; i < 4; i++) {
    int i2 = t + 64 * i;
    double2 a = Rr[i2];
    double x0, x1;
    if (sec) { x0 = t1d[i2 * 2]; x1 = t1d[i2 * 2 + 1]; }
    else     { x0 = bv[i2 * 2];  x1 = bv[i2 * 2 + 1]; }
    acc += a.x * x0 + a.y * x1;
  }
  acc = wredD(acc);
  if (t == 0) { if (sec) y1[m] = acc; else y0[m] = acc; }
}

// t1d[m] = fp64 dot(A[m,:], v), 512 blocks x 256. [proven R6]
__global__ __launch_bounds__(256) void k_mv_A(const float* __restrict__ Mat,
                                              const float* __restrict__ v,
                                              double* __restrict__ t1d,
                                              const int* __restrict__ flag, int chk) {
  if (chk && *flag) return;
  const int m = blockIdx.x, tid = threadIdx.x;
  const float4* Mr = (const float4*)(Mat + (size_t)m * Ncols);
  const float4* v4 = (const float4*)v;
  double acc = 0.0;
#pragma unroll
  for (int i = 0; i < 4; i++) {
    float4 a = Mr[tid + 256 * i];
    float4 x = v4[tid + 256 * i];
    acc += (double)a.x * x.x + (double)a.y * x.y + (double)a.z * x.z + (double)a.w * x.w;
  }
  __shared__ double sb[4];
  acc = wredD(acc);
  const int lane = tid & 63, wid = tid >> 6;
  if (!lane) sb[wid] = acc;
  __syncthreads();
  if (!tid) t1d[m] = sb[0] + sb[1] + sb[2] + sb[3];
}

// ---------------------------------------------------------------------------
// R16(c): tail fold - last CG dv-update folded into the final A*dv matvec.
// ---------------------------------------------------------------------------
__global__ __launch_bounds__(256) void k_mv_A_up(const float* __restrict__ A,
                                                 const float* __restrict__ p_last,
                                                 const float* __restrict__ dv,
                                                 float* __restrict__ dv2,
                                                 const double* __restrict__ dotbuf,
                                                 const int* __restrict__ flag,
                                                 double* __restrict__ t1d) {
  __shared__ double sdd[20];
  __shared__ double sb[4];
  const int tid = threadIdx.x;
  const int lane = tid & 63, wid = tid >> 6;
  double alpha = 0.0;
  if (!(*flag)) {
#pragma unroll
    for (int d = 0; d < 5; d++) {
      double v = dotbuf[d * 256 + tid];
      v = wredD(v);
      if (!lane) sdd[d * 4 + wid] = v;
    }
    __syncthreads();
    const double pPBp = sdd[0] + sdd[1] + sdd[2] + sdd[3];
    const double pp   = sdd[4] + sdd[5] + sdd[6] + sdd[7];
    const double rr   = sdd[16] + sdd[17] + sdd[18] + sdd[19];
    if (pPBp > 1e-6 * pp) alpha = rr / fmax(pPBp, 1e-300);
  }
  const int m = blockIdx.x;
  const float4* Mr = (const float4*)(A + (size_t)m * Ncols);
  const bool wb = (blockIdx.x < 16);
  double acc = 0.0;
#pragma unroll
  for (int i = 0; i < 4; i++) {
    const int i4 = tid + 256 * i;
    const float4 a  = Mr[i4];
    const float4 x  = ((const float4*)dv)[i4];
    const float4 pl = ((const float4*)p_last)[i4];
    const double x0 = (double)x.x + alpha * (double)pl.x;
    const double x1 = (double)x.y + alpha * (double)pl.y;
    const double x2 = (double)x.z + alpha * (double)pl.z;
    const double x3 = (double)x.w + alpha * (double)pl.w;
    acc += (double)a.x * x0 + (double)a.y * x1 + (double)a.z * x2 + (double)a.w * x3;
    if (wb && (i4 >> 6) == (int)blockIdx.x)
      ((float4*)dv2)[i4] = make_float4((float)x0, (float)x1, (float)x2, (float)x3);
  }
  acc = wredD(acc);
  if (!lane) sb[wid] = acc;
  __syncthreads();
  if (!tid) t1d[m] = sb[0] + sb[1] + sb[2] + sb[3];
}

// ---------------------------------------------------------------------------
// Bp = B p with the PREVIOUS iteration's CG update fused in (R11).
// ---------------------------------------------------------------------------
__global__ __launch_bounds__(256) void k_mv_B4u(const float* __restrict__ B,
                                                const float* __restrict__ p_prev,
                                                float* __restrict__ p_cur,
                                                const float* __restrict__ r_prev,
                                                float* __restrict__ r_cur,
                                                const float* __restrict__ PBp,
                                                const double* __restrict__ dotbuf,
                                                float* __restrict__ dv,
                                                float* __restrict__ Bp,
                                                int* __restrict__ flag, int upd) {
  if (flag[0]) return;
  __shared__ float4 ps[1024];
  __shared__ double sdd[20];
  const int tid = threadIdx.x;
  const int wid = tid >> 6, lane = tid & 63;
  if (!upd) {
#pragma unroll
    for (int l = 0; l < 4; l++)
      ps[tid + 256 * l] = ((const float4*)p_cur)[tid + 256 * l];
  } else {
#pragma unroll
    for (int d = 0; d < 5; d++) {
      double v = dotbuf[d * 256 + tid];
      v = wredD(v);
      if (!lane) sdd[d * 4 + wid] = v;
    }
    __syncthreads();
    double tot[5];
#pragma unroll
    for (int d = 0; d < 5; d++)
      tot[d] = sdd[d * 4] + sdd[d * 4 + 1] + sdd[d * 4 + 2] + sdd[d * 4 + 3];
    const double pPBp = tot[0], pp = tot[1], rPBp = tot[2], PBp2 = tot[3], rr = tot[4];
    if (pPBp <= 1e-6 * pp) { if (tid == 0) flag[0] = 1; return; }
    const double alpha = rr / fmax(pPBp, 1e-300);
    double rn2 = rr - 2.0 * alpha * rPBp + alpha * alpha * PBp2;
    rn2 = fmax(rn2, 0.0);
    const double beta = rn2 / fmax(rr, 1e-300);
    const bool wb = (blockIdx.x < 16);
#pragma unroll
    for (int l = 0; l < 4; l++) {
      const int i4 = tid + 256 * l;
      const float4 pv = ((const float4*)p_prev)[i4];
      const float4 rv = ((const float4*)r_prev)[i4];
      const float4 qv = ((const float4*)PBp)[i4];
      const double rd0 = (double)rv.x - alpha * (double)qv.x;
      const double rd1 = (double)rv.y - alpha * (double)qv.y;
      const double rd2 = (double)rv.z - alpha * (double)qv.z;
      const double rd3 = (double)rv.w - alpha * (double)qv.w;
      const float4 pn = make_float4((float)(rd0 + beta * (double)pv.x),
                                    (float)(rd1 + beta * (double)pv.y),
                                    (float)(rd2 + beta * (double)pv.z),
                                    (float)(rd3 + beta * (double)pv.w));
      ps[i4] = pn;
      if (wb && (i4 >> 6) == (int)blockIdx.x) {
        ((float4*)p_cur)[i4] = pn;
        ((float4*)r_cur)[i4] =
            make_float4((float)rd0, (float)rd1, (float)rd2, (float)rd3);
        float4 dvv = ((float4*)dv)[i4];
        dvv.x = (float)((double)dvv.x + alpha * (double)pv.x);
        dvv.y = (float)((double)dvv.y + alpha * (double)pv.y);
        dvv.z = (float)((double)dvv.z + alpha * (double)pv.z);
        dvv.w = (float)((double)dvv.w + alpha * (double)pv.w);
        ((float4*)dv)[i4] = dvv;
      }
    }
    if (rn2 < 1e-16) {  // converged: updates written, skip this matvec
      if (tid == 0 && blockIdx.x == 0) flag[0] = 1;
      return;
    }
  }
  __syncthreads();
  const int row = blockIdx.x * 4 + wid;
  const float4* Br = (const float4*)(B + (size_t)row * Ncols);
  double acc = 0.0;
#pragma unroll
  for (int i = 0; i < 16; i++) {
    const float4 a = Br[lane + 64 * i];
    const float4 x = ps[lane + 64 * i];
    acc += (double)a.x * x.x + (double)a.y * x.y + (double)a.z * x.z + (double)a.w * x.w;
  }
  acc = wredD(acc);
  if (!lane) Bp[row] = (float)acc;
}

// Setup outputs + CG init. [proven R6]
__global__ __launch_bounds__(256) void k_setup_fin(const float* __restrict__ A,
                                                   const double* __restrict__ y0d,
                                                   const double* __restrict__ y1d,
                                                   const float* __restrict__ g,
                                                   float* __restrict__ out,
                                                   float* __restrict__ r,
                                                   float* __restrict__ p,
                                                   float* __restrict__ dv) {
  __shared__ double y0s[512], y1s[512];
  const int tid = threadIdx.x;
  y0s[tid] = y0d[tid]; y0s[tid + 256] = y0d[tid + 256];
  y1s[tid] = y1d[tid]; y1s[tid + 256] = y1d[tid + 256];
  __syncthreads();
  const int col = blockIdx.x * 256 + tid;
  double xa = 0.0, ra = 0.0;
  for (int m = 0; m < Mrows; m++) {
    double av = (double)A[(size_t)m * Ncols + col];
    xa += av * y0s[m];
    ra += av * y1s[m];
  }
  out[col] = (float)xa;
  float rv = (float)(ra - (double)g[col]);
  r[col] = rv; p[col] = rv; dv[col] = 0.f;
}

// ---------------------------------------------------------------------------
// PBp = Bp - A^T y ; fresh fp64 dots {p.PBp, p.p, r.PBp, PBp.PBp, r.r}
// -> dotbuf[d*256 + bid]. 256 blocks x 256 thr, 16 cols/block, m 16-split.
// ---------------------------------------------------------------------------
__global__ __launch_bounds__(256) void k_pcc3(const float* __restrict__ A,
                                              const double* __restrict__ yd,
                                              const float* __restrict__ Bp,
                                              const float* __restrict__ p,
                                              const float* __restrict__ r,
                                              float* __restrict__ PBp,
                                              double* __restrict__ dotbuf,
                                              const int* __restrict__ flag) {
  if (*flag) return;
  __shared__ double ysh[512];
  __shared__ double part[256];
  __shared__ double d5[80];
  const int tid = threadIdx.x;
  ysh[tid] = yd[tid]; ysh[tid + 256] = yd[tid + 256];
  __syncthreads();
  const int cl = tid & 15, ms = tid >> 4;
  const int col = blockIdx.x * 16 + cl;
  double acc = 0.0;
  for (int m = ms * 32; m < ms * 32 + 32; m++)
    acc += (double)A[(size_t)m * Ncols + col] * ysh[m];
  part[ms * 16 + cl] = acc;
  __syncthreads();
  if (tid < 16) {
    const int c = blockIdx.x * 16 + tid;
    double s = 0.0;
#pragma unroll
    for (int q = 0; q < 16; q++) s += part[q * 16 + tid];
    const double pb = (double)Bp[c] - s;
    PBp[c] = (float)pb;
    const double pi = (double)p[c];
    const double ri = (double)r[c];
    d5[0 * 16 + tid] = pi * pb;
    d5[1 * 16 + tid] = pi * pi;
    d5[2 * 16 + tid] = ri * pb;
    d5[3 * 16 + tid] = pb * pb;
    d5[4 * 16 + tid] = ri * ri;
  }
  __syncthreads();
  if (tid < 5) {
    double s = 0.0;
#pragma unroll
    for (int c = 0; c < 16; c++) s += d5[tid * 16 + c];
    dotbuf[tid * 256 + blockIdx.x] = s;
  }
}

// out[4096+col] = dv2[col] - (A^T yd)[col]. [proven R6]
__global__ __launch_bounds__(256) void k_final_d(const float* __restrict__ A,
                                                 const double* __restrict__ yd,
                                                 const float* __restrict__ dv2,
                                                 float* __restrict__ out) {
  __shared__ double ysm[512];
  const int tid = threadIdx.x;
  ysm[tid] = yd[tid]; ysm[tid + 256] = yd[tid + 256];
  __syncthreads();
  const int col = blockIdx.x * 256 + tid;
  double acc = 0.0;
  for (int m = 0; m < Mrows; m++) acc += (double)A[(size_t)m * Ncols + col] * ysm[m];
  out[Ncols + col] = (float)((double)dv2[col] - acc);
}

// ---------------------------------------------------------------------------
extern "C" void kernel_launch(void* const* d_in, const int* in_sizes, int n_in,
                              void* d_out, int out_size, void* d_ws, size_t ws_size,
                              hipStream_t stream) {
  const float* A = (const float*)d_in[0];   // 512 x 4096
  const float* b = (const float*)d_in[1];   // 512
  const float* B = (const float*)d_in[2];   // 4096 x 4096
  const float* g = (const float*)d_in[3];   // 4096
  float* out = (float*)d_out;               // x[4096] then d[4096]
  float* ws = (float*)d_ws;

  // Ordering-safe aliasing: aat writes P[0..31] (ws+1048576..9437184 floats)
  // FIRST; redG consumes; everything placed in that range is written later.
  // Refinement temporaries PU/PV live at the HIGH end (5767168..7864320),
  // clear of Rd (3145728..3670016) and the CG block (3670016..3708432),
  // and are dead before k_setup_fin runs.
  float*  G   = ws;                         // 262144 floats
  float*  Xa  = ws + 262144;
  float*  Xb  = ws + 524288;
  float*  P   = ws + 1048576;               // 32 x 262144 (AAT) / 8 (NS)
  double* Ed  = (double*)(ws + 1048576);    // aliases P (post-NS only)
  float*  Eff = ws + 2621440;               // float(E), 262144 floats
  double* Rd  = (double*)(ws + 3145728);    // 512x512 fp64
  float*  Bp  = ws + 3670016;               // 4096 each
  float*  PBp = ws + 3674112;
  float*  r   = ws + 3678208;
  float*  p   = ws + 3682304;
  float*  dv  = ws + 3686400;
  double* t1d = (double*)(ws + 3690496);    // 512 doubles
  double* y0d = (double*)(ws + 3691520);
  double* y1d = (double*)(ws + 3692544);
  double* dotbuf = (double*)(ws + 3693568); // 5 x 256 doubles
  int*    flag   = (int*)(ws + 3696132);
  float*  p2  = ws + 3696144;               // ping-pong partners (R11)
  float*  r2  = ws + 3700240;
  float*  dv2 = ws + 3704336;               // R16(c) final-dv ping-pong
  float*  PU  = ws + 5767168;               // 4 x 262144 (R17 U-partials)
  float*  PV  = ws + 6815744;               // 4 x 262144 (R17 V-partials)

  // --- G = A A^T (32 K-slices, 128^2 tiles, 8x8/thread) ; row-reduce ---
  k_aat_part<<<dim3(4, 4, 32), 256, 0, stream>>>(A, P);
  k_redG<<<Mrows, 64, 0, stream>>>(P, G);

  // --- X0 = c0 I + c1 G + c2 G^2 (degree-2 Chebyshev) ---
  k_ns_a<<<dim3(8, 8, 4), 256, 0, stream>>>(G, G, P);          // P[0..3] = G*G
  k_init2s<<<256, 256, 0, stream>>>(Xa, G, P, flag);

  // --- Newton-Schulz: X' = 2X - X(GX), 2 iters, 3 kernels each ---
  float* Xcur = Xa;
  float* Xnxt = Xb;
  for (int it = 0; it < 2; it++) {
    k_ns_a<<<dim3(8, 8, 4), 256, 0, stream>>>(G, Xcur, P);      // P[0..3] = G*X
    k_ns_b<<<dim3(8, 8, 4), 256, 0, stream>>>(Xcur, P, P + 4 * 262144);  // P[4..7] = X*T
    k_ns_c<<<256, 256, 0, stream>>>(Xcur, P, Xnxt);             // Xn = 2X - sum
    float* tmp = Xcur; Xcur = Xnxt; Xnxt = tmp;
  }

  // --- R = X + X*E + (X*E)*E, E = I - G X (R17: 1 fp64 GEMM + 2 fp32) ---
  k_gemm_E<<<dim3(16, 16), 256, 0, stream>>>(G, Xcur, Ed, Eff);
  k_ns_a<<<dim3(8, 8, 4), 256, 0, stream>>>(Xcur, Eff, PU);     // PU = X*Ef
  k_uef<<<dim3(8, 8, 4), 256, 0, stream>>>(PU, Eff, PV);        // PV = U*Ef
  k_Rasm<<<256, 256, 0, stream>>>(Xcur, PU, PV, Rd);            // R = X+U+V

  // --- x = A^T R b ; r0 = p = A^T R (A g) - g  (merged solveRs, R16) ---
  k_mv_A<<<Mrows, 256, 0, stream>>>(A, g, t1d, flag, 0);
  k_solveR2<<<2 * Mrows, 64, 0, stream>>>(Rd, b, t1d, y0d, y1d);
  k_setup_fin<<<16, 256, 0, stream>>>(A, y0d, y1d, g, out, r, p, dv);

  // --- projected CG, CG_ITERS iterations, 4 launches/iter ---
  float* pb[2] = {p, p2};
  float* rb[2] = {r, r2};
  for (int it = 0; it < CG_ITERS; it++) {
    const int cur = it & 1, prv = cur ^ 1;
    if (it == 0)
      k_mv_B4u<<<1024, 256, 0, stream>>>(B, pb[0], pb[0], rb[0], rb[0], PBp,
                                         dotbuf, dv, Bp, flag, 0);
    else
      k_mv_B4u<<<1024, 256, 0, stream>>>(B, pb[prv], pb[cur], rb[prv], rb[cur],
                                         PBp, dotbuf, dv, Bp, flag, 1);
    k_mv_A<<<Mrows, 256, 0, stream>>>(A, Bp, t1d, flag, 1);
    k_solveR<<<Mrows, 64, 0, stream>>>(Rd, (const float*)0, t1d, y1d, flag, 1);
    k_pcc3<<<256, 256, 0, stream>>>(A, y1d, Bp, pb[cur], rb[cur], PBp, dotbuf, flag);
  }

  // --- d_out = P(dv + alpha p_last): fold + strip row-space (R16(c)) ---
  k_mv_A_up<<<Mrows, 256, 0, stream>>>(A, pb[(CG_ITERS - 1) & 1], dv, dv2,
                                       dotbuf, flag, t1d);
  k_solveR<<<Mrows, 64, 0, stream>>>(Rd, (const float*)0, t1d, y1d, flag, 0);
  k_final_d<<<16, 256, 0, stream>>>(A, y1d, dv2, out);
}